// Round 1
// baseline (5891.109 us; speedup 1.0000x reference)
//
#include <hip/hip_runtime.h>

#define N_NODE 100000
#define N_EDGE 1000000
#define HID 64
#define ATTN 32
#define REL_VOCAB 2005

__device__ __forceinline__ float sigf(float x){ return 1.0f/(1.0f+__expf(-x)); }

// dot of a 64-float register row (as float4[16]) with a uniform-address weight row
__device__ __forceinline__ float dot64(const float4* a, const float4* __restrict__ w){
  float s0=0.f,s1=0.f,s2=0.f,s3=0.f;
  #pragma unroll
  for (int i=0;i<16;i++){
    float4 av=a[i]; float4 wv=w[i];
    s0=fmaf(av.x,wv.x,s0); s1=fmaf(av.y,wv.y,s1);
    s2=fmaf(av.z,wv.z,s2); s3=fmaf(av.w,wv.w,s3);
  }
  return (s0+s1)+(s2+s3);
}

// Per-relation precompute:
//  layer0: alpha0[r] = sigmoid(relu(re0[r]@Wr0^T)@ww0 + wb0); scaledRel[r] = alpha0[r]*re0[r]
//  layer1: hrW1[r][j] = re1[r] @ Wr1[j]
__global__ void k_pre(const float* __restrict__ re, const float* __restrict__ Wr,
                      const float* __restrict__ ww, const float* __restrict__ wb,
                      float* __restrict__ scaledRel, float* __restrict__ hrW1)
{
  int r = blockIdx.x*blockDim.x + threadIdx.x;
  if (r >= REL_VOCAB) return;

  float4 e0[16];
  const float4* re0 = (const float4*)(re + r*HID);
  #pragma unroll
  for (int i=0;i<16;i++) e0[i]=re0[i];

  float acc = wb[0];
  #pragma unroll
  for (int j=0;j<ATTN;j++){
    float d = dot64(e0, (const float4*)(Wr + j*HID));       // layer 0 rows
    d = fmaxf(d, 0.f);
    acc = fmaf(d, ww[j], acc);
  }
  float alpha = sigf(acc);

  float4* srl = (float4*)(scaledRel + r*HID);
  #pragma unroll
  for (int i=0;i<16;i++){
    float4 v=e0[i];
    v.x*=alpha; v.y*=alpha; v.z*=alpha; v.w*=alpha;
    srl[i]=v;
  }

  float4 e1[16];
  const float4* re1 = (const float4*)(re + (REL_VOCAB + r)*HID);
  #pragma unroll
  for (int i=0;i<16;i++) e1[i]=re1[i];
  #pragma unroll
  for (int j=0;j<ATTN;j++)
    hrW1[r*ATTN+j] = dot64(e1, (const float4*)(Wr + (ATTN+j)*HID)); // layer 1 rows
}

__global__ void k_zero(float4* __restrict__ p, int n4){
  int i = blockIdx.x*blockDim.x + threadIdx.x;
  if (i < n4) p[i] = make_float4(0.f,0.f,0.f,0.f);
}

// layer-0 edge scatter: agg[obj] += scaledRel[rel]; 64 lanes per edge
__global__ void k_edge0(const int* __restrict__ edges, const float* __restrict__ scaledRel,
                        float* __restrict__ agg)
{
  int t = blockIdx.x*blockDim.x + threadIdx.x;
  int e = t >> 6; int k = t & 63;
  if (e >= N_EDGE) return;
  int rel = edges[e*6+2];
  int obj = edges[e*6+5];
  atomicAdd(&agg[obj*HID + k], scaledRel[rel*HID + k]);
}

// layer-1 edge kernel: one thread per edge
__global__ void __launch_bounds__(256) k_edge1(
    const int* __restrict__ edges, const float* __restrict__ h,
    const float* __restrict__ hrW1, const float* __restrict__ re1,
    const float* __restrict__ Ws1, const float* __restrict__ ww1,
    const float* __restrict__ wb1, float* __restrict__ agg)
{
  int e = blockIdx.x*blockDim.x + threadIdx.x;
  if (e >= N_EDGE) return;
  int sub = edges[e*6+4];
  int rel = edges[e*6+2];
  int obj = edges[e*6+5];

  float4 hs[16];
  const float4* hp = (const float4*)(h + sub*HID);
  #pragma unroll
  for (int i=0;i<16;i++) hs[i]=hp[i];

  float a[ATTN];
  const float* hw = hrW1 + rel*ATTN;
  #pragma unroll
  for (int j=0;j<ATTN;j++) a[j]=hw[j];

  const float4* ws = (const float4*)Ws1;   // uniform -> scalar loads
  #pragma unroll
  for (int j=0;j<ATTN;j++)
    a[j] += dot64(hs, ws + j*16);

  float acc = wb1[0];
  #pragma unroll
  for (int j=0;j<ATTN;j++){
    float d = fmaxf(a[j], 0.f);
    acc = fmaf(d, ww1[j], acc);
  }
  float alpha = sigf(acc);

  const float4* hr = (const float4*)(re1 + rel*HID);
  float* ap = agg + obj*HID;
  #pragma unroll
  for (int i=0;i<16;i++){
    float4 hv = hr[i];
    float mx = alpha*(hs[i].x+hv.x);
    float my = alpha*(hs[i].y+hv.y);
    float mz = alpha*(hs[i].z+hv.z);
    float mw = alpha*(hs[i].w+hv.w);
    atomicAdd(ap + i*4 + 0, mx);
    atomicAdd(ap + i*4 + 1, my);
    atomicAdd(ap + i*4 + 2, mz);
    atomicAdd(ap + i*4 + 3, mw);
  }
}

// node kernel: hidden = relu(agg@Wh^T); h' = GRU(hidden, h0); writes h in place.
// thread per node; all W reads are wave-uniform -> scalar loads.
__global__ void k_node(const float* __restrict__ agg, float* __restrict__ h,
                       const float* __restrict__ Wh, const float* __restrict__ Wih,
                       const float* __restrict__ Whh, const float* __restrict__ bih,
                       const float* __restrict__ bhh, int has_h0)
{
  int n = blockIdx.x*blockDim.x + threadIdx.x;
  if (n >= N_NODE) return;

  float4 av[16];
  const float4* ap = (const float4*)(agg + n*HID);
  #pragma unroll
  for (int i=0;i<16;i++) av[i]=ap[i];

  // x = relu(agg @ Wh^T)   (fully unrolled so x4 is compile-time indexed)
  float4 x4[16];
  #pragma unroll
  for (int m4=0;m4<16;m4++){
    float4 xv;
    xv.x = fmaxf(dot64(av,(const float4*)(Wh+(m4*4+0)*HID)),0.f);
    xv.y = fmaxf(dot64(av,(const float4*)(Wh+(m4*4+1)*HID)),0.f);
    xv.z = fmaxf(dot64(av,(const float4*)(Wh+(m4*4+2)*HID)),0.f);
    xv.w = fmaxf(dot64(av,(const float4*)(Wh+(m4*4+3)*HID)),0.f);
    x4[m4]=xv;
  }

  float* hp = h + n*HID;
  float4 h4[16];
  if (has_h0){
    const float4* hpp=(const float4*)hp;
    #pragma unroll
    for (int i=0;i<16;i++) h4[i]=hpp[i];
  } else {
    #pragma unroll
    for (int i=0;i<16;i++) h4[i]=make_float4(0.f,0.f,0.f,0.f);
  }

  // GRU; outer loop kept runtime to bound code size.
  for (int m4=0;m4<16;m4++){
    float o0,o1,o2,o3;
    #pragma unroll
    for (int c=0;c<4;c++){
      int m = m4*4+c;
      float gir = dot64(x4,(const float4*)(Wih+(m)*HID))     + bih[m];
      float giz = dot64(x4,(const float4*)(Wih+(64+m)*HID))  + bih[64+m];
      float gin = dot64(x4,(const float4*)(Wih+(128+m)*HID)) + bih[128+m];
      float ghr = bhh[m], ghz = bhh[64+m], ghn = bhh[128+m];
      if (has_h0){
        ghr += dot64(h4,(const float4*)(Whh+(m)*HID));
        ghz += dot64(h4,(const float4*)(Whh+(64+m)*HID));
        ghn += dot64(h4,(const float4*)(Whh+(128+m)*HID));
      }
      float r  = sigf(gir+ghr);
      float z  = sigf(giz+ghz);
      float nn = tanhf(fmaf(r, ghn, gin));
      float hv = has_h0 ? hp[m] : 0.f;     // reload own row (L1 hit) to avoid runtime reg-array index
      float o  = (1.f-z)*nn + z*hv;
      if (c==0) o0=o; else if (c==1) o1=o; else if (c==2) o2=o; else o3=o;
    }
    ((float4*)hp)[m4] = make_float4(o0,o1,o2,o3);  // h4 reg copy already holds old row for dots
  }
}

__global__ void k_score(const float* __restrict__ h, const float* __restrict__ wf,
                        float* __restrict__ out)
{
  int n = blockIdx.x*blockDim.x + threadIdx.x;
  if (n >= N_NODE) return;
  float4 hv[16];
  const float4* hp=(const float4*)(h+n*HID);
  #pragma unroll
  for (int i=0;i<16;i++) hv[i]=hp[i];
  out[n] = dot64(hv,(const float4*)wf);
}

extern "C" void kernel_launch(void* const* d_in, const int* in_sizes, int n_in,
                              void* d_out, int out_size, void* d_ws, size_t ws_size,
                              hipStream_t stream)
{
  const int*   edges = (const int*)  d_in[0];
  const float* re    = (const float*)d_in[1];
  const float* Ws    = (const float*)d_in[2];
  const float* Wr    = (const float*)d_in[3];
  const float* ww    = (const float*)d_in[4];
  const float* wb    = (const float*)d_in[5];
  const float* Wh    = (const float*)d_in[6];
  const float* Wih   = (const float*)d_in[7];
  const float* Whh   = (const float*)d_in[8];
  const float* bih   = (const float*)d_in[9];
  const float* bhh   = (const float*)d_in[10];
  const float* wf    = (const float*)d_in[11];
  float* out = (float*)d_out;

  float* h         = (float*)d_ws;                 // N_NODE*HID
  float* agg       = h   + (size_t)N_NODE*HID;     // N_NODE*HID
  float* scaledRel = agg + (size_t)N_NODE*HID;     // REL_VOCAB*HID
  float* hrW1      = scaledRel + REL_VOCAB*HID;    // REL_VOCAB*ATTN

  const int AGG4 = N_NODE*HID/4;

  // precompute per-relation tables
  k_pre<<<(REL_VOCAB+255)/256, 256, 0, stream>>>(re, Wr, ww, wb, scaledRel, hrW1);

  // ---- layer 0 ----
  k_zero<<<(AGG4+255)/256, 256, 0, stream>>>((float4*)agg, AGG4);
  k_edge0<<<(N_EDGE*64)/256, 256, 0, stream>>>(edges, scaledRel, agg);
  k_node<<<(N_NODE+255)/256, 256, 0, stream>>>(agg, h,
        Wh, Wih, Whh, bih, bhh, 0);

  // ---- layer 1 ----
  k_zero<<<(AGG4+255)/256, 256, 0, stream>>>((float4*)agg, AGG4);
  k_edge1<<<(N_EDGE+255)/256, 256, 0, stream>>>(edges, h, hrW1,
        re + (size_t)REL_VOCAB*HID, Ws + ATTN*HID, ww + ATTN, wb + 1, agg);
  k_node<<<(N_NODE+255)/256, 256, 0, stream>>>(agg, h,
        Wh + HID*HID, Wih + 3*HID*HID, Whh + 3*HID*HID, bih + 3*HID, bhh + 3*HID, 1);

  // scores
  k_score<<<(N_NODE+255)/256, 256, 0, stream>>>(h, wf, out);
}

// Round 2
// 2932.809 us; speedup vs baseline: 2.0087x; 2.0087x over previous
//
#include <hip/hip_runtime.h>

#define N_NODE 100000
#define N_EDGE 1000000
#define HID 64
#define ATTN 32
#define REL_VOCAB 2005
#define SCAN_M (N_NODE + 1)
#define SCAN_NB ((SCAN_M + 1023) / 1024)

__device__ __forceinline__ float sigf(float x){ return 1.0f/(1.0f+__expf(-x)); }

__device__ __forceinline__ float dot64(const float4* a, const float4* __restrict__ w){
  float s0=0.f,s1=0.f,s2=0.f,s3=0.f;
  #pragma unroll
  for (int i=0;i<16;i++){
    float4 av=a[i]; float4 wv=w[i];
    s0=fmaf(av.x,wv.x,s0); s1=fmaf(av.y,wv.y,s1);
    s2=fmaf(av.z,wv.z,s2); s3=fmaf(av.w,wv.w,s3);
  }
  return (s0+s1)+(s2+s3);
}

// ---- per-relation precompute (unchanged) ----
__global__ void k_pre(const float* __restrict__ re, const float* __restrict__ Wr,
                      const float* __restrict__ ww, const float* __restrict__ wb,
                      float* __restrict__ scaledRel, float* __restrict__ hrW1)
{
  int r = blockIdx.x*blockDim.x + threadIdx.x;
  if (r >= REL_VOCAB) return;

  float4 e0[16];
  const float4* re0 = (const float4*)(re + r*HID);
  #pragma unroll
  for (int i=0;i<16;i++) e0[i]=re0[i];

  float acc = wb[0];
  #pragma unroll
  for (int j=0;j<ATTN;j++){
    float d = dot64(e0, (const float4*)(Wr + j*HID));
    d = fmaxf(d, 0.f);
    acc = fmaf(d, ww[j], acc);
  }
  float alpha = sigf(acc);

  float4* srl = (float4*)(scaledRel + r*HID);
  #pragma unroll
  for (int i=0;i<16;i++){
    float4 v=e0[i];
    v.x*=alpha; v.y*=alpha; v.z*=alpha; v.w*=alpha;
    srl[i]=v;
  }

  float4 e1[16];
  const float4* re1 = (const float4*)(re + (REL_VOCAB + r)*HID);
  #pragma unroll
  for (int i=0;i<16;i++) e1[i]=re1[i];
  #pragma unroll
  for (int j=0;j<ATTN;j++)
    hrW1[r*ATTN+j] = dot64(e1, (const float4*)(Wr + (ATTN+j)*HID));
}

__global__ void k_zero(float4* __restrict__ p, int n4){
  int i = blockIdx.x*blockDim.x + threadIdx.x;
  if (i < n4) p[i] = make_float4(0.f,0.f,0.f,0.f);
}

// ---- counting sort of edges by obj ----
__global__ void k_hist(const int* __restrict__ edges, int* __restrict__ count){
  int e = blockIdx.x*blockDim.x + threadIdx.x;
  if (e >= N_EDGE) return;
  atomicAdd(&count[edges[e*6+5]], 1);
}

// block-level exclusive scan (1024/block); writes partial exclusive scans + block sums
__global__ void k_scan1(const int* __restrict__ count, int* __restrict__ start,
                        int* __restrict__ bsum)
{
  __shared__ int s[1024];
  int tid = threadIdx.x;
  int i = blockIdx.x*1024 + tid;
  int v = (i < SCAN_M) ? count[i] : 0;
  s[tid] = v; __syncthreads();
  #pragma unroll
  for (int off=1; off<1024; off<<=1){
    int t = (tid>=off) ? s[tid-off] : 0;
    __syncthreads();
    s[tid] += t;
    __syncthreads();
  }
  if (i < SCAN_M) start[i] = s[tid] - v;       // exclusive
  if (tid == 1023) bsum[blockIdx.x] = s[1023]; // block total
}

__global__ void k_scan2(const int* __restrict__ bsum, int* __restrict__ boff){
  if (threadIdx.x == 0){
    int run = 0;
    for (int b=0;b<SCAN_NB;b++){ boff[b]=run; run+=bsum[b]; }
  }
}

__global__ void k_scan3(int* __restrict__ start, const int* __restrict__ boff,
                        int* __restrict__ cursor)
{
  int i = blockIdx.x*1024 + threadIdx.x;
  if (i >= SCAN_M) return;
  int v = start[i] + boff[blockIdx.x];
  start[i] = v;
  if (i < N_NODE) cursor[i] = v;
}

__global__ void k_scatter(const int* __restrict__ edges, int* __restrict__ cursor,
                          int* __restrict__ sorted)
{
  int e = blockIdx.x*blockDim.x + threadIdx.x;
  if (e >= N_EDGE) return;
  int obj = edges[e*6+5];
  int pos = atomicAdd(&cursor[obj], 1);
  sorted[pos] = e;
}

// ---- layer-0 aggregation: wave per node, lane k owns channel k ----
__global__ void k_agg0(const int* __restrict__ edges, const int* __restrict__ start,
                       const int* __restrict__ sorted, const float* __restrict__ scaledRel,
                       float* __restrict__ agg)
{
  int t = blockIdx.x*blockDim.x + threadIdx.x;
  int n = t >> 6, k = t & 63;
  if (n >= N_NODE) return;
  int b = start[n], e_ = start[n+1];
  float acc = 0.f;
  for (int i=b; i<e_; ++i){
    int e = sorted[i];
    int rel = edges[e*6+2];
    acc += scaledRel[rel*HID + k];
  }
  agg[n*HID + k] = acc;
}

// ---- layer-1 per-edge alpha ----
__global__ void __launch_bounds__(256) k_alpha(
    const int* __restrict__ edges, const float* __restrict__ h,
    const float* __restrict__ hrW1, const float* __restrict__ Ws1,
    const float* __restrict__ ww1, const float* __restrict__ wb1,
    float* __restrict__ alpha)
{
  int e = blockIdx.x*blockDim.x + threadIdx.x;
  if (e >= N_EDGE) return;
  int sub = edges[e*6+4];
  int rel = edges[e*6+2];

  float4 hs[16];
  const float4* hp = (const float4*)(h + sub*HID);
  #pragma unroll
  for (int i=0;i<16;i++) hs[i]=hp[i];

  float a[ATTN];
  const float* hw = hrW1 + rel*ATTN;
  #pragma unroll
  for (int j=0;j<ATTN;j++) a[j]=hw[j];

  const float4* ws = (const float4*)Ws1;   // uniform -> scalar loads
  #pragma unroll
  for (int j=0;j<ATTN;j++)
    a[j] += dot64(hs, ws + j*16);

  float acc = wb1[0];
  #pragma unroll
  for (int j=0;j<ATTN;j++){
    float d = fmaxf(a[j], 0.f);
    acc = fmaf(d, ww1[j], acc);
  }
  alpha[e] = sigf(acc);
}

// ---- layer-1 aggregation: wave per node ----
__global__ void k_agg1(const int* __restrict__ edges, const int* __restrict__ start,
                       const int* __restrict__ sorted, const float* __restrict__ h,
                       const float* __restrict__ re1, const float* __restrict__ alpha,
                       float* __restrict__ agg)
{
  int t = blockIdx.x*blockDim.x + threadIdx.x;
  int n = t >> 6, k = t & 63;
  if (n >= N_NODE) return;
  int b = start[n], e_ = start[n+1];
  float acc = 0.f;
  for (int i=b; i<e_; ++i){
    int e = sorted[i];
    int rel = edges[e*6+2];
    int sub = edges[e*6+4];
    float al = alpha[e];
    acc += al * (h[sub*HID + k] + re1[rel*HID + k]);
  }
  agg[n*HID + k] = acc;
}

// ---- node phase: relu(agg@Wh^T) then GRU; writes h in place ----
__global__ void k_node(const float* __restrict__ agg, float* __restrict__ h,
                       const float* __restrict__ Wh, const float* __restrict__ Wih,
                       const float* __restrict__ Whh, const float* __restrict__ bih,
                       const float* __restrict__ bhh, int has_h0)
{
  int n = blockIdx.x*blockDim.x + threadIdx.x;
  if (n >= N_NODE) return;

  float4 av[16];
  const float4* ap = (const float4*)(agg + n*HID);
  #pragma unroll
  for (int i=0;i<16;i++) av[i]=ap[i];

  float4 x4[16];
  #pragma unroll
  for (int m4=0;m4<16;m4++){
    float4 xv;
    xv.x = fmaxf(dot64(av,(const float4*)(Wh+(m4*4+0)*HID)),0.f);
    xv.y = fmaxf(dot64(av,(const float4*)(Wh+(m4*4+1)*HID)),0.f);
    xv.z = fmaxf(dot64(av,(const float4*)(Wh+(m4*4+2)*HID)),0.f);
    xv.w = fmaxf(dot64(av,(const float4*)(Wh+(m4*4+3)*HID)),0.f);
    x4[m4]=xv;
  }

  float* hp = h + n*HID;
  float4 h4[16];
  if (has_h0){
    const float4* hpp=(const float4*)hp;
    #pragma unroll
    for (int i=0;i<16;i++) h4[i]=hpp[i];
  } else {
    #pragma unroll
    for (int i=0;i<16;i++) h4[i]=make_float4(0.f,0.f,0.f,0.f);
  }

  for (int m4=0;m4<16;m4++){
    float o0,o1,o2,o3;
    #pragma unroll
    for (int c=0;c<4;c++){
      int m = m4*4+c;
      float gir = dot64(x4,(const float4*)(Wih+(m)*HID))     + bih[m];
      float giz = dot64(x4,(const float4*)(Wih+(64+m)*HID))  + bih[64+m];
      float gin = dot64(x4,(const float4*)(Wih+(128+m)*HID)) + bih[128+m];
      float ghr = bhh[m], ghz = bhh[64+m], ghn = bhh[128+m];
      if (has_h0){
        ghr += dot64(h4,(const float4*)(Whh+(m)*HID));
        ghz += dot64(h4,(const float4*)(Whh+(64+m)*HID));
        ghn += dot64(h4,(const float4*)(Whh+(128+m)*HID));
      }
      float r  = sigf(gir+ghr);
      float z  = sigf(giz+ghz);
      float nn = tanhf(fmaf(r, ghn, gin));
      float hv = has_h0 ? hp[m] : 0.f;
      float o  = (1.f-z)*nn + z*hv;
      if (c==0) o0=o; else if (c==1) o1=o; else if (c==2) o2=o; else o3=o;
    }
    ((float4*)hp)[m4] = make_float4(o0,o1,o2,o3);
  }
}

__global__ void k_score(const float* __restrict__ h, const float* __restrict__ wf,
                        float* __restrict__ out)
{
  int n = blockIdx.x*blockDim.x + threadIdx.x;
  if (n >= N_NODE) return;
  float4 hv[16];
  const float4* hp=(const float4*)(h+n*HID);
  #pragma unroll
  for (int i=0;i<16;i++) hv[i]=hp[i];
  out[n] = dot64(hv,(const float4*)wf);
}

extern "C" void kernel_launch(void* const* d_in, const int* in_sizes, int n_in,
                              void* d_out, int out_size, void* d_ws, size_t ws_size,
                              hipStream_t stream)
{
  const int*   edges = (const int*)  d_in[0];
  const float* re    = (const float*)d_in[1];
  const float* Ws    = (const float*)d_in[2];
  const float* Wr    = (const float*)d_in[3];
  const float* ww    = (const float*)d_in[4];
  const float* wb    = (const float*)d_in[5];
  const float* Wh    = (const float*)d_in[6];
  const float* Wih   = (const float*)d_in[7];
  const float* Whh   = (const float*)d_in[8];
  const float* bih   = (const float*)d_in[9];
  const float* bhh   = (const float*)d_in[10];
  const float* wf    = (const float*)d_in[11];
  float* out = (float*)d_out;

  // workspace layout
  float* h         = (float*)d_ws;                       // N_NODE*HID
  float* agg       = h   + (size_t)N_NODE*HID;           // N_NODE*HID
  float* scaledRel = agg + (size_t)N_NODE*HID;           // REL_VOCAB*HID
  float* hrW1      = scaledRel + REL_VOCAB*HID;          // REL_VOCAB*ATTN
  float* alphaBuf  = hrW1 + REL_VOCAB*ATTN;              // N_EDGE
  int*   count     = (int*)(alphaBuf + N_EDGE);          // 100004 (padded)
  int*   startArr  = count + 100004;                     // 100004
  int*   cursor    = startArr + 100004;                  // 100004
  int*   bsum      = cursor + 100004;                    // 128
  int*   boff      = bsum + 128;                         // 128
  int*   sorted    = boff + 128;                         // N_EDGE

  // ---- counting sort of edges by obj ----
  k_zero<<<(100004/4+255)/256, 256, 0, stream>>>((float4*)count, 100004/4);
  k_hist<<<(N_EDGE+255)/256, 256, 0, stream>>>(edges, count);
  k_scan1<<<SCAN_NB, 1024, 0, stream>>>(count, startArr, bsum);
  k_scan2<<<1, 64, 0, stream>>>(bsum, boff);
  k_scan3<<<SCAN_NB, 1024, 0, stream>>>(startArr, boff, cursor);
  k_scatter<<<(N_EDGE+255)/256, 256, 0, stream>>>(edges, cursor, sorted);

  // ---- per-relation tables ----
  k_pre<<<(REL_VOCAB+255)/256, 256, 0, stream>>>(re, Wr, ww, wb, scaledRel, hrW1);

  // ---- layer 0 ----
  k_agg0<<<(N_NODE*64)/256, 256, 0, stream>>>(edges, startArr, sorted, scaledRel, agg);
  k_node<<<(N_NODE+255)/256, 256, 0, stream>>>(agg, h,
        Wh, Wih, Whh, bih, bhh, 0);

  // ---- layer 1 ----
  k_alpha<<<(N_EDGE+255)/256, 256, 0, stream>>>(edges, h, hrW1,
        Ws + ATTN*HID, ww + ATTN, wb + 1, alphaBuf);
  k_agg1<<<(N_NODE*64)/256, 256, 0, stream>>>(edges, startArr, sorted, h,
        re + (size_t)REL_VOCAB*HID, alphaBuf, agg);
  k_node<<<(N_NODE+255)/256, 256, 0, stream>>>(agg, h,
        Wh + HID*HID, Wih + 3*HID*HID, Whh + 3*HID*HID, bih + 3*HID, bhh + 3*HID, 1);

  // ---- scores ----
  k_score<<<(N_NODE+255)/256, 256, 0, stream>>>(h, wf, out);
}

// Round 3
// 1700.221 us; speedup vs baseline: 3.4649x; 1.7250x over previous
//
#include <hip/hip_runtime.h>

#define N_NODE 100000
#define N_EDGE 1000000
#define HID 64
#define ATTN 32
#define REL_VOCAB 2005
#define SCAN_M (N_NODE + 1)
#define SCAN_NB ((SCAN_M + 1023) / 1024)

__device__ __forceinline__ float sigf(float x){ return 1.0f/(1.0f+__expf(-x)); }

__device__ __forceinline__ float dot64(const float4* a, const float4* __restrict__ w){
  float s0=0.f,s1=0.f,s2=0.f,s3=0.f;
  #pragma unroll
  for (int i=0;i<16;i++){
    float4 av=a[i]; float4 wv=w[i];
    s0=fmaf(av.x,wv.x,s0); s1=fmaf(av.y,wv.y,s1);
    s2=fmaf(av.z,wv.z,s2); s3=fmaf(av.w,wv.w,s3);
  }
  return (s0+s1)+(s2+s3);
}

// ---- per-relation precompute ----
__global__ void __launch_bounds__(256, 2) k_pre(
    const float* __restrict__ re, const float* __restrict__ Wr,
    const float* __restrict__ ww, const float* __restrict__ wb,
    float* __restrict__ scaledRel, float* __restrict__ hrW1)
{
  int r = blockIdx.x*blockDim.x + threadIdx.x;
  if (r >= REL_VOCAB) return;

  float4 e0[16];
  const float4* re0 = (const float4*)(re + r*HID);
  #pragma unroll
  for (int i=0;i<16;i++) e0[i]=re0[i];

  float acc = wb[0];
  #pragma unroll
  for (int j=0;j<ATTN;j++){
    float d = dot64(e0, (const float4*)(Wr + j*HID));
    d = fmaxf(d, 0.f);
    acc = fmaf(d, ww[j], acc);
  }
  float alpha = sigf(acc);

  float4* srl = (float4*)(scaledRel + r*HID);
  #pragma unroll
  for (int i=0;i<16;i++){
    float4 v=e0[i];
    v.x*=alpha; v.y*=alpha; v.z*=alpha; v.w*=alpha;
    srl[i]=v;
  }

  float4 e1[16];
  const float4* re1 = (const float4*)(re + (REL_VOCAB + r)*HID);
  #pragma unroll
  for (int i=0;i<16;i++) e1[i]=re1[i];
  #pragma unroll
  for (int j=0;j<ATTN;j++)
    hrW1[r*ATTN+j] = dot64(e1, (const float4*)(Wr + (ATTN+j)*HID));
}

__global__ void k_zero(float4* __restrict__ p, int n4){
  int i = blockIdx.x*blockDim.x + threadIdx.x;
  if (i < n4) p[i] = make_float4(0.f,0.f,0.f,0.f);
}

// ---- counting sort of edges by obj ----
__global__ void k_hist(const int* __restrict__ edges, int* __restrict__ count){
  int e = blockIdx.x*blockDim.x + threadIdx.x;
  if (e >= N_EDGE) return;
  atomicAdd(&count[edges[e*6+5]], 1);
}

__global__ void k_scan1(const int* __restrict__ count, int* __restrict__ start,
                        int* __restrict__ bsum)
{
  __shared__ int s[1024];
  int tid = threadIdx.x;
  int i = blockIdx.x*1024 + tid;
  int v = (i < SCAN_M) ? count[i] : 0;
  s[tid] = v; __syncthreads();
  #pragma unroll
  for (int off=1; off<1024; off<<=1){
    int t = (tid>=off) ? s[tid-off] : 0;
    __syncthreads();
    s[tid] += t;
    __syncthreads();
  }
  if (i < SCAN_M) start[i] = s[tid] - v;
  if (tid == 1023) bsum[blockIdx.x] = s[1023];
}

__global__ void k_scan2(const int* __restrict__ bsum, int* __restrict__ boff){
  if (threadIdx.x == 0){
    int run = 0;
    for (int b=0;b<SCAN_NB;b++){ boff[b]=run; run+=bsum[b]; }
  }
}

__global__ void k_scan3(int* __restrict__ start, const int* __restrict__ boff,
                        int* __restrict__ cursor)
{
  int i = blockIdx.x*1024 + threadIdx.x;
  if (i >= SCAN_M) return;
  int v = start[i] + boff[blockIdx.x];
  start[i] = v;
  if (i < N_NODE) cursor[i] = v;
}

__global__ void k_scatter(const int* __restrict__ edges, int* __restrict__ cursor,
                          int* __restrict__ sorted)
{
  int e = blockIdx.x*blockDim.x + threadIdx.x;
  if (e >= N_EDGE) return;
  int obj = edges[e*6+5];
  int pos = atomicAdd(&cursor[obj], 1);
  sorted[pos] = e;
}

// ---- layer-0 aggregation: wave per node, lane k owns channel k ----
__global__ void k_agg0(const int* __restrict__ edges, const int* __restrict__ start,
                       const int* __restrict__ sorted, const float* __restrict__ scaledRel,
                       float* __restrict__ agg)
{
  int t = blockIdx.x*blockDim.x + threadIdx.x;
  int n = t >> 6, k = t & 63;
  if (n >= N_NODE) return;
  int b = start[n], e_ = start[n+1];
  float acc = 0.f;
  for (int i=b; i<e_; ++i){
    int e = sorted[i];
    int rel = edges[e*6+2];
    acc += scaledRel[rel*HID + k];
  }
  agg[n*HID + k] = acc;
}

// ---- layer-1 per-edge alpha ----
__global__ void __launch_bounds__(256, 2) k_alpha(
    const int* __restrict__ edges, const float* __restrict__ h,
    const float* __restrict__ hrW1, const float* __restrict__ Ws1,
    const float* __restrict__ ww1, const float* __restrict__ wb1,
    float* __restrict__ alpha)
{
  int e = blockIdx.x*blockDim.x + threadIdx.x;
  if (e >= N_EDGE) return;
  int sub = edges[e*6+4];
  int rel = edges[e*6+2];

  float4 hs[16];
  const float4* hp = (const float4*)(h + sub*HID);
  #pragma unroll
  for (int i=0;i<16;i++) hs[i]=hp[i];

  float a[ATTN];
  const float* hw = hrW1 + rel*ATTN;
  #pragma unroll
  for (int j=0;j<ATTN;j++) a[j]=hw[j];

  const float4* ws = (const float4*)Ws1;   // uniform -> scalar loads
  #pragma unroll
  for (int j=0;j<ATTN;j++)
    a[j] += dot64(hs, ws + j*16);

  float acc = wb1[0];
  #pragma unroll
  for (int j=0;j<ATTN;j++){
    float d = fmaxf(a[j], 0.f);
    acc = fmaf(d, ww1[j], acc);
  }
  alpha[e] = sigf(acc);
}

// ---- layer-1 aggregation: wave per node ----
__global__ void k_agg1(const int* __restrict__ edges, const int* __restrict__ start,
                       const int* __restrict__ sorted, const float* __restrict__ h,
                       const float* __restrict__ re1, const float* __restrict__ alpha,
                       float* __restrict__ agg)
{
  int t = blockIdx.x*blockDim.x + threadIdx.x;
  int n = t >> 6, k = t & 63;
  if (n >= N_NODE) return;
  int b = start[n], e_ = start[n+1];
  float acc = 0.f;
  for (int i=b; i<e_; ++i){
    int e = sorted[i];
    int rel = edges[e*6+2];
    int sub = edges[e*6+4];
    float al = alpha[e];
    acc += al * (h[sub*HID + k] + re1[rel*HID + k]);
  }
  agg[n*HID + k] = acc;
}

// ---- node phase: relu(agg@Wh^T) then GRU; writes h in place ----
// __launch_bounds__(256,2): VGPR cap 256 so av/x4/h4 stay in registers (spill
// at the default 1024-thread budget cost 3 GB of scratch HBM traffic).
__global__ void __launch_bounds__(256, 2) k_node(
    const float* __restrict__ agg, float* __restrict__ h,
    const float* __restrict__ Wh, const float* __restrict__ Wih,
    const float* __restrict__ Whh, const float* __restrict__ bih,
    const float* __restrict__ bhh, int has_h0)
{
  int n = blockIdx.x*blockDim.x + threadIdx.x;
  if (n >= N_NODE) return;

  float4 x4[16];
  {
    float4 av[16];
    const float4* ap = (const float4*)(agg + n*HID);
    #pragma unroll
    for (int i=0;i<16;i++) av[i]=ap[i];

    #pragma unroll
    for (int m4=0;m4<16;m4++){
      float4 xv;
      xv.x = fmaxf(dot64(av,(const float4*)(Wh+(m4*4+0)*HID)),0.f);
      xv.y = fmaxf(dot64(av,(const float4*)(Wh+(m4*4+1)*HID)),0.f);
      xv.z = fmaxf(dot64(av,(const float4*)(Wh+(m4*4+2)*HID)),0.f);
      xv.w = fmaxf(dot64(av,(const float4*)(Wh+(m4*4+3)*HID)),0.f);
      x4[m4]=xv;
    }
  }

  float* hp = h + n*HID;
  float4 h4[16];
  if (has_h0){
    const float4* hpp=(const float4*)hp;
    #pragma unroll
    for (int i=0;i<16;i++) h4[i]=hpp[i];
  } else {
    #pragma unroll
    for (int i=0;i<16;i++) h4[i]=make_float4(0.f,0.f,0.f,0.f);
  }

  for (int m4=0;m4<16;m4++){
    float o0,o1,o2,o3;
    #pragma unroll
    for (int c=0;c<4;c++){
      int m = m4*4+c;
      float gir = dot64(x4,(const float4*)(Wih+(m)*HID))     + bih[m];
      float giz = dot64(x4,(const float4*)(Wih+(64+m)*HID))  + bih[64+m];
      float gin = dot64(x4,(const float4*)(Wih+(128+m)*HID)) + bih[128+m];
      float ghr = bhh[m], ghz = bhh[64+m], ghn = bhh[128+m];
      if (has_h0){
        ghr += dot64(h4,(const float4*)(Whh+(m)*HID));
        ghz += dot64(h4,(const float4*)(Whh+(64+m)*HID));
        ghn += dot64(h4,(const float4*)(Whh+(128+m)*HID));
      }
      float r  = sigf(gir+ghr);
      float z  = sigf(giz+ghz);
      float nn = tanhf(fmaf(r, ghn, gin));
      float hv = has_h0 ? hp[m] : 0.f;  // L1 hit; avoids runtime reg-array index
      float o  = (1.f-z)*nn + z*hv;
      if (c==0) o0=o; else if (c==1) o1=o; else if (c==2) o2=o; else o3=o;
    }
    ((float4*)hp)[m4] = make_float4(o0,o1,o2,o3);
  }
}

__global__ void __launch_bounds__(256, 4) k_score(
    const float* __restrict__ h, const float* __restrict__ wf,
    float* __restrict__ out)
{
  int n = blockIdx.x*blockDim.x + threadIdx.x;
  if (n >= N_NODE) return;
  float4 hv[16];
  const float4* hp=(const float4*)(h+n*HID);
  #pragma unroll
  for (int i=0;i<16;i++) hv[i]=hp[i];
  out[n] = dot64(hv,(const float4*)wf);
}

extern "C" void kernel_launch(void* const* d_in, const int* in_sizes, int n_in,
                              void* d_out, int out_size, void* d_ws, size_t ws_size,
                              hipStream_t stream)
{
  const int*   edges = (const int*)  d_in[0];
  const float* re    = (const float*)d_in[1];
  const float* Ws    = (const float*)d_in[2];
  const float* Wr    = (const float*)d_in[3];
  const float* ww    = (const float*)d_in[4];
  const float* wb    = (const float*)d_in[5];
  const float* Wh    = (const float*)d_in[6];
  const float* Wih   = (const float*)d_in[7];
  const float* Whh   = (const float*)d_in[8];
  const float* bih   = (const float*)d_in[9];
  const float* bhh   = (const float*)d_in[10];
  const float* wf    = (const float*)d_in[11];
  float* out = (float*)d_out;

  // workspace layout
  float* h         = (float*)d_ws;                       // N_NODE*HID
  float* agg       = h   + (size_t)N_NODE*HID;           // N_NODE*HID
  float* scaledRel = agg + (size_t)N_NODE*HID;           // REL_VOCAB*HID
  float* hrW1      = scaledRel + REL_VOCAB*HID;          // REL_VOCAB*ATTN
  float* alphaBuf  = hrW1 + REL_VOCAB*ATTN;              // N_EDGE
  int*   count     = (int*)(alphaBuf + N_EDGE);          // 100004 (padded)
  int*   startArr  = count + 100004;                     // 100004
  int*   cursor    = startArr + 100004;                  // 100004
  int*   bsum      = cursor + 100004;                    // 128
  int*   boff      = bsum + 128;                         // 128
  int*   sorted    = boff + 128;                         // N_EDGE

  // ---- counting sort of edges by obj ----
  k_zero<<<(100004/4+255)/256, 256, 0, stream>>>((float4*)count, 100004/4);
  k_hist<<<(N_EDGE+255)/256, 256, 0, stream>>>(edges, count);
  k_scan1<<<SCAN_NB, 1024, 0, stream>>>(count, startArr, bsum);
  k_scan2<<<1, 64, 0, stream>>>(bsum, boff);
  k_scan3<<<SCAN_NB, 1024, 0, stream>>>(startArr, boff, cursor);
  k_scatter<<<(N_EDGE+255)/256, 256, 0, stream>>>(edges, cursor, sorted);

  // ---- per-relation tables ----
  k_pre<<<(REL_VOCAB+255)/256, 256, 0, stream>>>(re, Wr, ww, wb, scaledRel, hrW1);

  // ---- layer 0 ----
  k_agg0<<<(N_NODE*64)/256, 256, 0, stream>>>(edges, startArr, sorted, scaledRel, agg);
  k_node<<<(N_NODE+255)/256, 256, 0, stream>>>(agg, h,
        Wh, Wih, Whh, bih, bhh, 0);

  // ---- layer 1 ----
  k_alpha<<<(N_EDGE+255)/256, 256, 0, stream>>>(edges, h, hrW1,
        Ws + ATTN*HID, ww + ATTN, wb + 1, alphaBuf);
  k_agg1<<<(N_NODE*64)/256, 256, 0, stream>>>(edges, startArr, sorted, h,
        re + (size_t)REL_VOCAB*HID, alphaBuf, agg);
  k_node<<<(N_NODE+255)/256, 256, 0, stream>>>(agg, h,
        Wh + HID*HID, Wih + 3*HID*HID, Whh + 3*HID*HID, bih + 3*HID, bhh + 3*HID, 1);

  // ---- scores ----
  k_score<<<(N_NODE+255)/256, 256, 0, stream>>>(h, wf, out);
}

// Round 4
// 745.104 us; speedup vs baseline: 7.9064x; 2.2819x over previous
//
#include <hip/hip_runtime.h>

#define N_NODE 100000
#define N_EDGE 1000000
#define HID 64
#define ATTN 32
#define REL_VOCAB 2005
#define SCAN_M (N_NODE + 1)
#define SCAN_NB ((SCAN_M + 1023) / 1024)

__device__ __forceinline__ float sigf(float x){ return 1.0f/(1.0f+__expf(-x)); }

__device__ __forceinline__ float dot64(const float4* a, const float4* __restrict__ w){
  float s0=0.f,s1=0.f,s2=0.f,s3=0.f;
  #pragma unroll
  for (int i=0;i<16;i++){
    float4 av=a[i]; float4 wv=w[i];
    s0=fmaf(av.x,wv.x,s0); s1=fmaf(av.y,wv.y,s1);
    s2=fmaf(av.z,wv.z,s2); s3=fmaf(av.w,wv.w,s3);
  }
  return (s0+s1)+(s2+s3);
}

// ---- per-relation precompute ----
__global__ void __launch_bounds__(256, 2) k_pre(
    const float* __restrict__ re, const float* __restrict__ Wr,
    const float* __restrict__ ww, const float* __restrict__ wb,
    float* __restrict__ scaledRel, float* __restrict__ hrW1)
{
  int r = blockIdx.x*blockDim.x + threadIdx.x;
  if (r >= REL_VOCAB) return;

  float4 e0[16];
  const float4* re0 = (const float4*)(re + r*HID);
  #pragma unroll
  for (int i=0;i<16;i++) e0[i]=re0[i];

  float acc = wb[0];
  #pragma unroll
  for (int j=0;j<ATTN;j++){
    float d = dot64(e0, (const float4*)(Wr + j*HID));
    d = fmaxf(d, 0.f);
    acc = fmaf(d, ww[j], acc);
  }
  float alpha = sigf(acc);

  float4* srl = (float4*)(scaledRel + r*HID);
  #pragma unroll
  for (int i=0;i<16;i++){
    float4 v=e0[i];
    v.x*=alpha; v.y*=alpha; v.z*=alpha; v.w*=alpha;
    srl[i]=v;
  }

  float4 e1[16];
  const float4* re1 = (const float4*)(re + (REL_VOCAB + r)*HID);
  #pragma unroll
  for (int i=0;i<16;i++) e1[i]=re1[i];
  #pragma unroll
  for (int j=0;j<ATTN;j++)
    hrW1[r*ATTN+j] = dot64(e1, (const float4*)(Wr + (ATTN+j)*HID));
}

__global__ void k_zero(float4* __restrict__ p, int n4){
  int i = blockIdx.x*blockDim.x + threadIdx.x;
  if (i < n4) p[i] = make_float4(0.f,0.f,0.f,0.f);
}

// ---- weight transpose: k-major layouts for the node-phase GEMM ----
// Wh_t[li][k*64+m] = Wh[li][m*64+k]; Wih_t/Whh_t[li][k*192+gm] = W[li][gm*64+k]
__global__ void k_wt(const float* __restrict__ Wh, const float* __restrict__ Wih,
                     const float* __restrict__ Whh, float* __restrict__ Wh_t,
                     float* __restrict__ Wih_t, float* __restrict__ Whh_t)
{
  int tid = blockIdx.x*blockDim.x + threadIdx.x;
  if (tid >= 2*28672) return;
  int li = tid / 28672, r = tid % 28672;
  if (r < 4096){
    int k = r / 64, m = r % 64;
    Wh_t[li*4096 + k*64 + m] = Wh[li*4096 + m*64 + k];
  } else if (r < 16384){
    int q = r - 4096; int k = q / 192, gm = q % 192;
    Wih_t[li*12288 + k*192 + gm] = Wih[li*12288 + gm*64 + k];
  } else {
    int q = r - 16384; int k = q / 192, gm = q % 192;
    Whh_t[li*12288 + k*192 + gm] = Whh[li*12288 + gm*64 + k];
  }
}

// ---- counting sort of edges by obj ----
__global__ void k_hist(const int* __restrict__ edges, int* __restrict__ count){
  int e = blockIdx.x*blockDim.x + threadIdx.x;
  if (e >= N_EDGE) return;
  atomicAdd(&count[edges[e*6+5]], 1);
}

__global__ void k_scan1(const int* __restrict__ count, int* __restrict__ start,
                        int* __restrict__ bsum)
{
  __shared__ int s[1024];
  int tid = threadIdx.x;
  int i = blockIdx.x*1024 + tid;
  int v = (i < SCAN_M) ? count[i] : 0;
  s[tid] = v; __syncthreads();
  #pragma unroll
  for (int off=1; off<1024; off<<=1){
    int t = (tid>=off) ? s[tid-off] : 0;
    __syncthreads();
    s[tid] += t;
    __syncthreads();
  }
  if (i < SCAN_M) start[i] = s[tid] - v;
  if (tid == 1023) bsum[blockIdx.x] = s[1023];
}

__global__ void k_scan2(const int* __restrict__ bsum, int* __restrict__ boff){
  if (threadIdx.x == 0){
    int run = 0;
    for (int b=0;b<SCAN_NB;b++){ boff[b]=run; run+=bsum[b]; }
  }
}

__global__ void k_scan3(int* __restrict__ start, const int* __restrict__ boff,
                        int* __restrict__ cursor)
{
  int i = blockIdx.x*1024 + threadIdx.x;
  if (i >= SCAN_M) return;
  int v = start[i] + boff[blockIdx.x];
  start[i] = v;
  if (i < N_NODE) cursor[i] = v;
}

__global__ void k_scatter(const int* __restrict__ edges, int* __restrict__ cursor,
                          int* __restrict__ sorted)
{
  int e = blockIdx.x*blockDim.x + threadIdx.x;
  if (e >= N_EDGE) return;
  int obj = edges[e*6+5];
  int pos = atomicAdd(&cursor[obj], 1);
  sorted[pos] = e;
}

// ---- layer-0 aggregation: wave per node, lane k owns channel k ----
__global__ void k_agg0(const int* __restrict__ edges, const int* __restrict__ start,
                       const int* __restrict__ sorted, const float* __restrict__ scaledRel,
                       float* __restrict__ agg)
{
  int t = blockIdx.x*blockDim.x + threadIdx.x;
  int n = t >> 6, k = t & 63;
  if (n >= N_NODE) return;
  int b = start[n], e_ = start[n+1];
  float acc = 0.f;
  for (int i=b; i<e_; ++i){
    int e = sorted[i];
    int rel = edges[e*6+2];
    acc += scaledRel[rel*HID + k];
  }
  agg[n*HID + k] = acc;
}

// ---- layer-1 per-edge alpha ----
__global__ void __launch_bounds__(256, 2) k_alpha(
    const int* __restrict__ edges, const float* __restrict__ h,
    const float* __restrict__ hrW1, const float* __restrict__ Ws1,
    const float* __restrict__ ww1, const float* __restrict__ wb1,
    float* __restrict__ alpha)
{
  int e = blockIdx.x*blockDim.x + threadIdx.x;
  if (e >= N_EDGE) return;
  int sub = edges[e*6+4];
  int rel = edges[e*6+2];

  float4 hs[16];
  const float4* hp = (const float4*)(h + (size_t)sub*HID);
  #pragma unroll
  for (int i=0;i<16;i++) hs[i]=hp[i];

  float a[ATTN];
  const float* hw = hrW1 + rel*ATTN;
  #pragma unroll
  for (int j=0;j<ATTN;j++) a[j]=hw[j];

  const float4* ws = (const float4*)Ws1;
  #pragma unroll
  for (int j=0;j<ATTN;j++)
    a[j] += dot64(hs, ws + j*16);

  float acc = wb1[0];
  #pragma unroll
  for (int j=0;j<ATTN;j++){
    float d = fmaxf(a[j], 0.f);
    acc = fmaf(d, ww1[j], acc);
  }
  alpha[e] = sigf(acc);
}

// ---- layer-1 aggregation: wave per node ----
__global__ void k_agg1(const int* __restrict__ edges, const int* __restrict__ start,
                       const int* __restrict__ sorted, const float* __restrict__ h,
                       const float* __restrict__ re1, const float* __restrict__ alpha,
                       float* __restrict__ agg)
{
  int t = blockIdx.x*blockDim.x + threadIdx.x;
  int n = t >> 6, k = t & 63;
  if (n >= N_NODE) return;
  int b = start[n], e_ = start[n+1];
  float acc = 0.f;
  for (int i=b; i<e_; ++i){
    int e = sorted[i];
    int rel = edges[e*6+2];
    int sub = edges[e*6+4];
    float al = alpha[e];
    acc += al * (h[(size_t)sub*HID + k] + re1[rel*HID + k]);
  }
  agg[n*HID + k] = acc;
}

// ---- fused node phase: tile of 64 nodes per block, 256 threads ----
// phase 1: stage agg tile transposed in LDS; stage h_t tile (k-major global).
// phase 2: x = relu(agg @ Wh^T) -> LDS (each thread: lane=node, 16 channels)
// phase 3: 6 GRU gate GEMMs into 96 register accumulators; GRU epilogue.
// All weight reads wave-uniform (readfirstlane) -> scalar loads.
__global__ void __launch_bounds__(256, 2) k_node2(
    const float* __restrict__ agg, const float* __restrict__ h_t_prev,
    const float* __restrict__ Wh_t, const float* __restrict__ Wih_t,
    const float* __restrict__ Whh_t, const float* __restrict__ bih,
    const float* __restrict__ bhh,
    float* __restrict__ h, float* __restrict__ h_t_out,
    int has_h0, int write_ht)
{
  __shared__ float sagg[HID][64];   // [k][node]
  __shared__ float sx[HID][64];     // [k][node]
  __shared__ float sh[HID][64];     // [k][node]

  const int t = threadIdx.x;
  const int n0 = blockIdx.x * 64;

  // ---- phase 1: staging ----
  {
    const int nr = t >> 2;           // node row within tile
    const int kc = (t & 3) * 16;     // k chunk
    const int n  = n0 + nr;
    float va[16];
    if (n < N_NODE){
      const float4* ap = (const float4*)(agg + (size_t)n*HID + kc);
      float4 a0=ap[0], a1=ap[1], a2=ap[2], a3=ap[3];
      va[0]=a0.x; va[1]=a0.y; va[2]=a0.z; va[3]=a0.w;
      va[4]=a1.x; va[5]=a1.y; va[6]=a1.z; va[7]=a1.w;
      va[8]=a2.x; va[9]=a2.y; va[10]=a2.z; va[11]=a2.w;
      va[12]=a3.x; va[13]=a3.y; va[14]=a3.z; va[15]=a3.w;
    } else {
      #pragma unroll
      for (int j=0;j<16;j++) va[j]=0.f;
    }
    #pragma unroll
    for (int j=0;j<16;j++) sagg[kc+j][nr] = va[j];

    if (has_h0){
      // h_t_prev is k-major [64][N_NODE]; copy coalesced.
      // (may read <=31 floats past column N_NODE for last tile; h_t is
      //  mid-workspace so the read stays in allocated memory; values unused)
      const float4* hp = (const float4*)(h_t_prev + (size_t)nr*N_NODE + n0 + kc);
      float4 b0=hp[0], b1=hp[1], b2=hp[2], b3=hp[3];
      *(float4*)&sh[nr][kc]    = b0;
      *(float4*)&sh[nr][kc+4]  = b1;
      *(float4*)&sh[nr][kc+8]  = b2;
      *(float4*)&sh[nr][kc+12] = b3;
    }
  }
  __syncthreads();

  const int l  = t & 63;
  const int m0 = __builtin_amdgcn_readfirstlane((t >> 6) * 16);

  // ---- phase 2: x = relu(agg @ Wh^T), 16 channels per thread ----
  float xa[16];
  #pragma unroll
  for (int c=0;c<16;c++) xa[c]=0.f;
  for (int k=0;k<HID;k++){
    float av = sagg[k][l];
    const float* wt = Wh_t + k*HID + m0;
    #pragma unroll
    for (int c=0;c<16;c++) xa[c] = fmaf(av, wt[c], xa[c]);
  }
  #pragma unroll
  for (int c=0;c<16;c++) sx[m0+c][l] = fmaxf(xa[c], 0.f);
  __syncthreads();

  // ---- phase 3: GRU gate GEMMs ----
  float air[16],aiz[16],ain[16],ahr[16],ahz[16],ahn[16];
  #pragma unroll
  for (int c=0;c<16;c++){ air[c]=0.f; aiz[c]=0.f; ain[c]=0.f;
                          ahr[c]=0.f; ahz[c]=0.f; ahn[c]=0.f; }
  if (has_h0){
    for (int k=0;k<HID;k++){
      float xv = sx[k][l];
      float hv = sh[k][l];
      const float* wi = Wih_t + k*192 + m0;
      const float* wh = Whh_t + k*192 + m0;
      #pragma unroll
      for (int c=0;c<16;c++){
        air[c] = fmaf(xv, wi[c],     air[c]);
        aiz[c] = fmaf(xv, wi[64+c],  aiz[c]);
        ain[c] = fmaf(xv, wi[128+c], ain[c]);
      }
      #pragma unroll
      for (int c=0;c<16;c++){
        ahr[c] = fmaf(hv, wh[c],     ahr[c]);
        ahz[c] = fmaf(hv, wh[64+c],  ahz[c]);
        ahn[c] = fmaf(hv, wh[128+c], ahn[c]);
      }
    }
  } else {
    for (int k=0;k<HID;k++){
      float xv = sx[k][l];
      const float* wi = Wih_t + k*192 + m0;
      #pragma unroll
      for (int c=0;c<16;c++){
        air[c] = fmaf(xv, wi[c],     air[c]);
        aiz[c] = fmaf(xv, wi[64+c],  aiz[c]);
        ain[c] = fmaf(xv, wi[128+c], ain[c]);
      }
    }
  }

  // ---- GRU epilogue ----
  float ov[16];
  #pragma unroll
  for (int c=0;c<16;c++){
    int m = m0 + c;
    float gir = air[c] + bih[m];
    float giz = aiz[c] + bih[64+m];
    float gin = ain[c] + bih[128+m];
    float ghr = bhh[m], ghz = bhh[64+m], ghn = bhh[128+m];
    if (has_h0){ ghr += ahr[c]; ghz += ahz[c]; ghn += ahn[c]; }
    float r  = sigf(gir + ghr);
    float z  = sigf(giz + ghz);
    float nn = tanhf(fmaf(r, ghn, gin));
    float h0v = has_h0 ? sh[m0+c][l] : 0.f;
    ov[c] = (1.f - z)*nn + z*h0v;
  }

  const int n = n0 + l;
  if (n < N_NODE){
    float4* hp = (float4*)(h + (size_t)n*HID + m0);
    hp[0] = make_float4(ov[0], ov[1], ov[2], ov[3]);
    hp[1] = make_float4(ov[4], ov[5], ov[6], ov[7]);
    hp[2] = make_float4(ov[8], ov[9], ov[10], ov[11]);
    hp[3] = make_float4(ov[12],ov[13],ov[14],ov[15]);
    if (write_ht){
      #pragma unroll
      for (int c=0;c<16;c++)
        h_t_out[(size_t)(m0+c)*N_NODE + n] = ov[c];
    }
  }
}

__global__ void __launch_bounds__(256, 4) k_score(
    const float* __restrict__ h, const float* __restrict__ wf,
    float* __restrict__ out)
{
  int n = blockIdx.x*blockDim.x + threadIdx.x;
  if (n >= N_NODE) return;
  float4 hv[16];
  const float4* hp=(const float4*)(h+(size_t)n*HID);
  #pragma unroll
  for (int i=0;i<16;i++) hv[i]=hp[i];
  out[n] = dot64(hv,(const float4*)wf);
}

extern "C" void kernel_launch(void* const* d_in, const int* in_sizes, int n_in,
                              void* d_out, int out_size, void* d_ws, size_t ws_size,
                              hipStream_t stream)
{
  const int*   edges = (const int*)  d_in[0];
  const float* re    = (const float*)d_in[1];
  const float* Ws    = (const float*)d_in[2];
  const float* Wr    = (const float*)d_in[3];
  const float* ww    = (const float*)d_in[4];
  const float* wb    = (const float*)d_in[5];
  const float* Wh    = (const float*)d_in[6];
  const float* Wih   = (const float*)d_in[7];
  const float* Whh   = (const float*)d_in[8];
  const float* bih   = (const float*)d_in[9];
  const float* bhh   = (const float*)d_in[10];
  const float* wf    = (const float*)d_in[11];
  float* out = (float*)d_out;

  // workspace layout (floats)
  float* h         = (float*)d_ws;                       // 6,400,000
  float* agg       = h   + (size_t)N_NODE*HID;           // 6,400,000
  float* h_t       = agg + (size_t)N_NODE*HID;           // 6,400,000 (k-major)
  float* scaledRel = h_t + (size_t)N_NODE*HID;           // 128,320
  float* hrW1      = scaledRel + REL_VOCAB*HID;          // 64,160
  float* alphaBuf  = hrW1 + REL_VOCAB*ATTN;              // 1,000,000
  float* Wh_t      = alphaBuf + N_EDGE;                  // 8,192
  float* Wih_t     = Wh_t + 2*4096;                      // 24,576
  float* Whh_t     = Wih_t + 2*12288;                    // 24,576
  int*   count     = (int*)(Whh_t + 2*12288);            // 100,004
  int*   startArr  = count + 100004;                     // 100,004
  int*   cursor    = startArr + 100004;                  // 100,004
  int*   bsum      = cursor + 100004;                    // 128
  int*   boff      = bsum + 128;                         // 128
  int*   sorted    = boff + 128;                         // 1,000,000

  // ---- counting sort of edges by obj ----
  k_zero<<<(100004/4+255)/256, 256, 0, stream>>>((float4*)count, 100004/4);
  k_hist<<<(N_EDGE+255)/256, 256, 0, stream>>>(edges, count);
  k_scan1<<<SCAN_NB, 1024, 0, stream>>>(count, startArr, bsum);
  k_scan2<<<1, 64, 0, stream>>>(bsum, boff);
  k_scan3<<<SCAN_NB, 1024, 0, stream>>>(startArr, boff, cursor);
  k_scatter<<<(N_EDGE+255)/256, 256, 0, stream>>>(edges, cursor, sorted);

  // ---- per-relation tables + weight transposes ----
  k_pre<<<(REL_VOCAB+255)/256, 256, 0, stream>>>(re, Wr, ww, wb, scaledRel, hrW1);
  k_wt<<<(2*28672+255)/256, 256, 0, stream>>>(Wh, Wih, Whh, Wh_t, Wih_t, Whh_t);

  const int NB_NODE2 = (N_NODE + 63) / 64;

  // ---- layer 0 ----
  k_agg0<<<(N_NODE*64)/256, 256, 0, stream>>>(edges, startArr, sorted, scaledRel, agg);
  k_node2<<<NB_NODE2, 256, 0, stream>>>(agg, h_t,
        Wh_t, Wih_t, Whh_t, bih, bhh, h, h_t, 0, 1);

  // ---- layer 1 ----
  k_alpha<<<(N_EDGE+255)/256, 256, 0, stream>>>(edges, h, hrW1,
        Ws + ATTN*HID, ww + ATTN, wb + 1, alphaBuf);
  k_agg1<<<(N_NODE*64)/256, 256, 0, stream>>>(edges, startArr, sorted, h,
        re + (size_t)REL_VOCAB*HID, alphaBuf, agg);
  k_node2<<<NB_NODE2, 256, 0, stream>>>(agg, h_t,
        Wh_t + 4096, Wih_t + 12288, Whh_t + 12288, bih + 3*HID, bhh + 3*HID,
        h, h_t, 1, 0);

  // ---- scores ----
  k_score<<<(N_NODE+255)/256, 256, 0, stream>>>(h, wf, out);
}

// Round 5
// 505.223 us; speedup vs baseline: 11.6604x; 1.4748x over previous
//
#include <hip/hip_runtime.h>

#define N_NODE 100000
#define N_EDGE 1000000
#define HID 64
#define ATTN 32
#define REL_VOCAB 2005
#define SCAN_M (N_NODE + 1)
#define SCAN_NB ((SCAN_M + 1023) / 1024)

__device__ __forceinline__ float sigf(float x){ return 1.0f/(1.0f+__expf(-x)); }
__device__ __forceinline__ float bf2f(unsigned short u){
  return __uint_as_float(((unsigned int)u) << 16);
}
__device__ __forceinline__ unsigned short f2bf(float f){  // RNE
  unsigned int x = __float_as_uint(f);
  x += 0x7fffu + ((x >> 16) & 1u);
  return (unsigned short)(x >> 16);
}

__device__ __forceinline__ float dot64(const float4* a, const float4* __restrict__ w){
  float s0=0.f,s1=0.f,s2=0.f,s3=0.f;
  #pragma unroll
  for (int i=0;i<16;i++){
    float4 av=a[i]; float4 wv=w[i];
    s0=fmaf(av.x,wv.x,s0); s1=fmaf(av.y,wv.y,s1);
    s2=fmaf(av.z,wv.z,s2); s3=fmaf(av.w,wv.w,s3);
  }
  return (s0+s1)+(s2+s3);
}

// ---- per-relation precompute ----
__global__ void __launch_bounds__(256, 2) k_pre(
    const float* __restrict__ re, const float* __restrict__ Wr,
    const float* __restrict__ ww, const float* __restrict__ wb,
    float* __restrict__ scaledRel, float* __restrict__ hrW1)
{
  int r = blockIdx.x*blockDim.x + threadIdx.x;
  if (r >= REL_VOCAB) return;

  float4 e0[16];
  const float4* re0 = (const float4*)(re + r*HID);
  #pragma unroll
  for (int i=0;i<16;i++) e0[i]=re0[i];

  float acc = wb[0];
  #pragma unroll
  for (int j=0;j<ATTN;j++){
    float d = dot64(e0, (const float4*)(Wr + j*HID));
    d = fmaxf(d, 0.f);
    acc = fmaf(d, ww[j], acc);
  }
  float alpha = sigf(acc);

  float4* srl = (float4*)(scaledRel + r*HID);
  #pragma unroll
  for (int i=0;i<16;i++){
    float4 v=e0[i];
    v.x*=alpha; v.y*=alpha; v.z*=alpha; v.w*=alpha;
    srl[i]=v;
  }

  float4 e1[16];
  const float4* re1 = (const float4*)(re + (REL_VOCAB + r)*HID);
  #pragma unroll
  for (int i=0;i<16;i++) e1[i]=re1[i];
  #pragma unroll
  for (int j=0;j<ATTN;j++)
    hrW1[r*ATTN+j] = dot64(e1, (const float4*)(Wr + (ATTN+j)*HID));
}

__global__ void k_zero(float4* __restrict__ p, int n4){
  int i = blockIdx.x*blockDim.x + threadIdx.x;
  if (i < n4) p[i] = make_float4(0.f,0.f,0.f,0.f);
}

// ---- weight transpose: k-major layouts for the node-phase GEMM ----
__global__ void k_wt(const float* __restrict__ Wh, const float* __restrict__ Wih,
                     const float* __restrict__ Whh, float* __restrict__ Wh_t,
                     float* __restrict__ Wih_t, float* __restrict__ Whh_t)
{
  int tid = blockIdx.x*blockDim.x + threadIdx.x;
  if (tid >= 2*28672) return;
  int li = tid / 28672, r = tid % 28672;
  if (r < 4096){
    int k = r / 64, m = r % 64;
    Wh_t[li*4096 + k*64 + m] = Wh[li*4096 + m*64 + k];
  } else if (r < 16384){
    int q = r - 4096; int k = q / 192, gm = q % 192;
    Wih_t[li*12288 + k*192 + gm] = Wih[li*12288 + gm*64 + k];
  } else {
    int q = r - 16384; int k = q / 192, gm = q % 192;
    Whh_t[li*12288 + k*192 + gm] = Whh[li*12288 + gm*64 + k];
  }
}

// ---- counting sort of edges by obj ----
__global__ void k_hist(const int* __restrict__ edges, int* __restrict__ count){
  int e = blockIdx.x*blockDim.x + threadIdx.x;
  if (e >= N_EDGE) return;
  atomicAdd(&count[edges[e*6+5]], 1);
}

__global__ void k_scan1(const int* __restrict__ count, int* __restrict__ start,
                        int* __restrict__ bsum)
{
  __shared__ int s[1024];
  int tid = threadIdx.x;
  int i = blockIdx.x*1024 + tid;
  int v = (i < SCAN_M) ? count[i] : 0;
  s[tid] = v; __syncthreads();
  #pragma unroll
  for (int off=1; off<1024; off<<=1){
    int t = (tid>=off) ? s[tid-off] : 0;
    __syncthreads();
    s[tid] += t;
    __syncthreads();
  }
  if (i < SCAN_M) start[i] = s[tid] - v;
  if (tid == 1023) bsum[blockIdx.x] = s[1023];
}

__global__ void k_scan2(const int* __restrict__ bsum, int* __restrict__ boff){
  if (threadIdx.x == 0){
    int run = 0;
    for (int b=0;b<SCAN_NB;b++){ boff[b]=run; run+=bsum[b]; }
  }
}

__global__ void k_scan3(int* __restrict__ start, const int* __restrict__ boff,
                        int* __restrict__ cursor)
{
  int i = blockIdx.x*1024 + threadIdx.x;
  if (i >= SCAN_M) return;
  int v = start[i] + boff[blockIdx.x];
  start[i] = v;
  if (i < N_NODE) cursor[i] = v;
}

// scatter: write packed rel/sub in sorted-by-obj order (removes indirection)
__global__ void k_scatter(const int* __restrict__ edges, int* __restrict__ cursor,
                          int* __restrict__ relS, int* __restrict__ subS)
{
  int e = blockIdx.x*blockDim.x + threadIdx.x;
  if (e >= N_EDGE) return;
  int obj = edges[e*6+5];
  int rel = edges[e*6+2];
  int sub = edges[e*6+4];
  int pos = atomicAdd(&cursor[obj], 1);
  relS[pos] = rel;
  subS[pos] = sub;
}

// ---- layer-0 aggregation: wave per node, lane k owns channel k ----
__global__ void k_agg0(const int* __restrict__ startArr, const int* __restrict__ relS,
                       const float* __restrict__ scaledRel, float* __restrict__ agg)
{
  int t = blockIdx.x*blockDim.x + threadIdx.x;
  int n = __builtin_amdgcn_readfirstlane(t >> 6);
  int k = t & 63;
  if (n >= N_NODE) return;
  int b = startArr[n], e_ = startArr[n+1];
  float acc = 0.f;
  int i = b;
  for (; i+3 < e_; i += 4){
    int r0=relS[i], r1=relS[i+1], r2=relS[i+2], r3=relS[i+3];
    float v0=scaledRel[r0*HID+k], v1=scaledRel[r1*HID+k];
    float v2=scaledRel[r2*HID+k], v3=scaledRel[r3*HID+k];
    acc += v0; acc += v1; acc += v2; acc += v3;
  }
  for (; i < e_; ++i) acc += scaledRel[relS[i]*HID + k];
  agg[(size_t)n*HID + k] = acc;
}

// ---- layer-1 per-edge alpha (sorted order; bf16 h gather) ----
__global__ void __launch_bounds__(256, 2) k_alpha(
    const int* __restrict__ relS, const int* __restrict__ subS,
    const unsigned short* __restrict__ h16,
    const float* __restrict__ hrW1, const float* __restrict__ Ws1,
    const float* __restrict__ ww1, const float* __restrict__ wb1,
    float* __restrict__ alphaS)
{
  int i = blockIdx.x*blockDim.x + threadIdx.x;
  if (i >= N_EDGE) return;
  int sub = subS[i];
  int rel = relS[i];

  float hs[HID];
  const uint4* hp = (const uint4*)(h16 + (size_t)sub*HID);
  #pragma unroll
  for (int q=0;q<8;q++){
    uint4 u = hp[q];
    hs[q*8+0]=__uint_as_float(u.x<<16); hs[q*8+1]=__uint_as_float(u.x&0xffff0000u);
    hs[q*8+2]=__uint_as_float(u.y<<16); hs[q*8+3]=__uint_as_float(u.y&0xffff0000u);
    hs[q*8+4]=__uint_as_float(u.z<<16); hs[q*8+5]=__uint_as_float(u.z&0xffff0000u);
    hs[q*8+6]=__uint_as_float(u.w<<16); hs[q*8+7]=__uint_as_float(u.w&0xffff0000u);
  }

  const float* hw = hrW1 + rel*ATTN;
  float acc = wb1[0];
  #pragma unroll
  for (int j=0;j<ATTN;j++){
    float aj = hw[j];
    const float* wr = Ws1 + j*HID;   // uniform -> scalar loads
    #pragma unroll
    for (int k=0;k<HID;k++) aj = fmaf(hs[k], wr[k], aj);
    acc = fmaf(fmaxf(aj, 0.f), ww1[j], acc);
  }
  alphaS[i] = sigf(acc);
}

// ---- layer-1 aggregation: wave per node; bf16 h gather; 2-deep ILP ----
__global__ void k_agg1(const int* __restrict__ startArr, const int* __restrict__ relS,
                       const int* __restrict__ subS, const float* __restrict__ alphaS,
                       const unsigned short* __restrict__ h16,
                       const float* __restrict__ re1, float* __restrict__ agg)
{
  int t = blockIdx.x*blockDim.x + threadIdx.x;
  int n = __builtin_amdgcn_readfirstlane(t >> 6);
  int k = t & 63;
  if (n >= N_NODE) return;
  int b = startArr[n], e_ = startArr[n+1];
  float acc = 0.f;
  int i = b;
  for (; i+1 < e_; i += 2){
    int r0 = relS[i],   s0 = subS[i];
    int r1 = relS[i+1], s1 = subS[i+1];
    float al0 = alphaS[i], al1 = alphaS[i+1];
    float h0 = bf2f(h16[(size_t)s0*HID + k]);
    float h1 = bf2f(h16[(size_t)s1*HID + k]);
    float v0 = re1[r0*HID + k];
    float v1 = re1[r1*HID + k];
    acc = fmaf(al0, h0 + v0, acc);
    acc = fmaf(al1, h1 + v1, acc);
  }
  if (i < e_){
    int r0 = relS[i], s0 = subS[i];
    acc = fmaf(alphaS[i], bf2f(h16[(size_t)s0*HID + k]) + re1[r0*HID + k], acc);
  }
  agg[(size_t)n*HID + k] = acc;
}

// ---- fused node phase (64-node tile, 256 threads) ----
// mode 0: write h_t (k-major) + h16 (bf16 row-major).  mode 1: write scores.
__global__ void __launch_bounds__(256, 2) k_node2(
    const float* __restrict__ agg, const float* __restrict__ h_t_prev,
    const float* __restrict__ Wh_t, const float* __restrict__ Wih_t,
    const float* __restrict__ Whh_t, const float* __restrict__ bih,
    const float* __restrict__ bhh,
    float* __restrict__ h_t_out, unsigned short* __restrict__ h16_out,
    const float* __restrict__ wf, float* __restrict__ score,
    int has_h0, int mode)
{
  __shared__ float sagg[HID][64];   // [k][node]
  __shared__ float sx[HID][64];     // [k][node]
  __shared__ float sh[HID][64];     // [k][node]

  const int t = threadIdx.x;
  const int n0 = blockIdx.x * 64;

  // ---- phase 1: staging ----
  {
    const int nr = t >> 2;
    const int kc = (t & 3) * 16;
    const int nn = n0 + nr;
    float va[16];
    if (nn < N_NODE){
      const float4* ap = (const float4*)(agg + (size_t)nn*HID + kc);
      float4 a0=ap[0], a1=ap[1], a2=ap[2], a3=ap[3];
      va[0]=a0.x; va[1]=a0.y; va[2]=a0.z; va[3]=a0.w;
      va[4]=a1.x; va[5]=a1.y; va[6]=a1.z; va[7]=a1.w;
      va[8]=a2.x; va[9]=a2.y; va[10]=a2.z; va[11]=a2.w;
      va[12]=a3.x; va[13]=a3.y; va[14]=a3.z; va[15]=a3.w;
    } else {
      #pragma unroll
      for (int j=0;j<16;j++) va[j]=0.f;
    }
    #pragma unroll
    for (int j=0;j<16;j++) sagg[kc+j][nr] = va[j];

    if (has_h0){
      // h_t_prev k-major [64][N_NODE]; coalesced copy (<=31-float tail overread
      // stays inside the workspace; values for OOB nodes never used)
      const float4* hp = (const float4*)(h_t_prev + (size_t)nr*N_NODE + n0 + kc);
      float4 b0=hp[0], b1=hp[1], b2=hp[2], b3=hp[3];
      *(float4*)&sh[nr][kc]    = b0;
      *(float4*)&sh[nr][kc+4]  = b1;
      *(float4*)&sh[nr][kc+8]  = b2;
      *(float4*)&sh[nr][kc+12] = b3;
    }
  }
  __syncthreads();

  const int l  = t & 63;
  const int m0 = __builtin_amdgcn_readfirstlane((t >> 6) * 16);

  // ---- phase 2: x = relu(agg @ Wh^T) ----
  float xa[16];
  #pragma unroll
  for (int c=0;c<16;c++) xa[c]=0.f;
  for (int k=0;k<HID;k++){
    float av = sagg[k][l];
    const float* wt = Wh_t + k*HID + m0;
    #pragma unroll
    for (int c=0;c<16;c++) xa[c] = fmaf(av, wt[c], xa[c]);
  }
  #pragma unroll
  for (int c=0;c<16;c++) sx[m0+c][l] = fmaxf(xa[c], 0.f);
  __syncthreads();

  // ---- phase 3: GRU gate GEMMs ----
  float air[16],aiz[16],ain[16],ahr[16],ahz[16],ahn[16];
  #pragma unroll
  for (int c=0;c<16;c++){ air[c]=0.f; aiz[c]=0.f; ain[c]=0.f;
                          ahr[c]=0.f; ahz[c]=0.f; ahn[c]=0.f; }
  if (has_h0){
    for (int k=0;k<HID;k++){
      float xv = sx[k][l];
      float hv = sh[k][l];
      const float* wi = Wih_t + k*192 + m0;
      const float* wh = Whh_t + k*192 + m0;
      #pragma unroll
      for (int c=0;c<16;c++){
        air[c] = fmaf(xv, wi[c],     air[c]);
        aiz[c] = fmaf(xv, wi[64+c],  aiz[c]);
        ain[c] = fmaf(xv, wi[128+c], ain[c]);
      }
      #pragma unroll
      for (int c=0;c<16;c++){
        ahr[c] = fmaf(hv, wh[c],     ahr[c]);
        ahz[c] = fmaf(hv, wh[64+c],  ahz[c]);
        ahn[c] = fmaf(hv, wh[128+c], ahn[c]);
      }
    }
  } else {
    for (int k=0;k<HID;k++){
      float xv = sx[k][l];
      const float* wi = Wih_t + k*192 + m0;
      #pragma unroll
      for (int c=0;c<16;c++){
        air[c] = fmaf(xv, wi[c],     air[c]);
        aiz[c] = fmaf(xv, wi[64+c],  aiz[c]);
        ain[c] = fmaf(xv, wi[128+c], ain[c]);
      }
    }
  }

  // ---- GRU epilogue ----
  float ov[16];
  #pragma unroll
  for (int c=0;c<16;c++){
    int m = m0 + c;
    float gir = air[c] + bih[m];
    float giz = aiz[c] + bih[64+m];
    float gin = ain[c] + bih[128+m];
    float ghr = bhh[m], ghz = bhh[64+m], ghn = bhh[128+m];
    if (has_h0){ ghr += ahr[c]; ghz += ahz[c]; ghn += ahn[c]; }
    float r  = sigf(gir + ghr);
    float z  = sigf(giz + ghz);
    float nn = tanhf(fmaf(r, ghn, gin));
    float h0v = has_h0 ? sh[m0+c][l] : 0.f;
    ov[c] = (1.f - z)*nn + z*h0v;
  }

  const int n = n0 + l;
  if (mode == 1){
    // fused score = h @ W_final, reduced across the 4 waves via LDS
    float part = 0.f;
    #pragma unroll
    for (int c=0;c<16;c++) part = fmaf(ov[c], wf[m0+c], part);
    __syncthreads();                    // sagg free; sh reads done by all threads
    float* red = &sagg[0][0];
    red[(t>>6)*64 + l] = part;
    __syncthreads();
    if (t < 64){
      int nn2 = n0 + t;
      if (nn2 < N_NODE)
        score[nn2] = (red[t] + red[64+t]) + (red[128+t] + red[192+t]);
    }
  } else {
    if (n < N_NODE){
      #pragma unroll
      for (int c=0;c<16;c++)
        h_t_out[(size_t)(m0+c)*N_NODE + n] = ov[c];
      unsigned int p[8];
      #pragma unroll
      for (int q=0;q<8;q++){
        unsigned int lo = f2bf(ov[2*q]);
        unsigned int hi = f2bf(ov[2*q+1]);
        p[q] = lo | (hi << 16);
      }
      uint4* hp16 = (uint4*)(h16_out + (size_t)n*HID + m0);
      hp16[0] = make_uint4(p[0],p[1],p[2],p[3]);
      hp16[1] = make_uint4(p[4],p[5],p[6],p[7]);
    }
  }
}

extern "C" void kernel_launch(void* const* d_in, const int* in_sizes, int n_in,
                              void* d_out, int out_size, void* d_ws, size_t ws_size,
                              hipStream_t stream)
{
  const int*   edges = (const int*)  d_in[0];
  const float* re    = (const float*)d_in[1];
  const float* Ws    = (const float*)d_in[2];
  const float* Wr    = (const float*)d_in[3];
  const float* ww    = (const float*)d_in[4];
  const float* wb    = (const float*)d_in[5];
  const float* Wh    = (const float*)d_in[6];
  const float* Wih   = (const float*)d_in[7];
  const float* Whh   = (const float*)d_in[8];
  const float* bih   = (const float*)d_in[9];
  const float* bhh   = (const float*)d_in[10];
  const float* wf    = (const float*)d_in[11];
  float* out = (float*)d_out;

  // workspace layout (floats unless noted)
  float* agg       = (float*)d_ws;                       // 6,400,000
  float* h_t       = agg + (size_t)N_NODE*HID;           // 6,400,000 (k-major)
  unsigned short* h16 = (unsigned short*)(h_t + (size_t)N_NODE*HID); // 6,400,000 u16
  float* scaledRel = (float*)(h16 + (size_t)N_NODE*HID); // 128,320
  float* hrW1      = scaledRel + REL_VOCAB*HID;          // 64,160
  float* alphaS    = hrW1 + REL_VOCAB*ATTN;              // 1,000,000
  float* Wh_t      = alphaS + N_EDGE;                    // 8,192
  float* Wih_t     = Wh_t + 2*4096;                      // 24,576
  float* Whh_t     = Wih_t + 2*12288;                    // 24,576
  int*   count     = (int*)(Whh_t + 2*12288);            // 100,004
  int*   startArr  = count + 100004;                     // 100,004
  int*   cursor    = startArr + 100004;                  // 100,004
  int*   bsum      = cursor + 100004;                    // 128
  int*   boff      = bsum + 128;                         // 128
  int*   relS      = boff + 128;                         // 1,000,000
  int*   subS      = relS + N_EDGE;                      // 1,000,000

  // ---- counting sort of edges by obj (packed rel/sub) ----
  k_zero<<<(100004/4+255)/256, 256, 0, stream>>>((float4*)count, 100004/4);
  k_hist<<<(N_EDGE+255)/256, 256, 0, stream>>>(edges, count);
  k_scan1<<<SCAN_NB, 1024, 0, stream>>>(count, startArr, bsum);
  k_scan2<<<1, 64, 0, stream>>>(bsum, boff);
  k_scan3<<<SCAN_NB, 1024, 0, stream>>>(startArr, boff, cursor);
  k_scatter<<<(N_EDGE+255)/256, 256, 0, stream>>>(edges, cursor, relS, subS);

  // ---- per-relation tables + weight transposes ----
  k_pre<<<(REL_VOCAB+255)/256, 256, 0, stream>>>(re, Wr, ww, wb, scaledRel, hrW1);
  k_wt<<<(2*28672+255)/256, 256, 0, stream>>>(Wh, Wih, Whh, Wh_t, Wih_t, Whh_t);

  const int NB_NODE2 = (N_NODE + 63) / 64;

  // ---- layer 0 ----
  k_agg0<<<(N_NODE*64)/256, 256, 0, stream>>>(startArr, relS, scaledRel, agg);
  k_node2<<<NB_NODE2, 256, 0, stream>>>(agg, h_t,
        Wh_t, Wih_t, Whh_t, bih, bhh, h_t, h16, wf, out, 0, 0);

  // ---- layer 1 ----
  k_alpha<<<(N_EDGE+255)/256, 256, 0, stream>>>(relS, subS, h16, hrW1,
        Ws + ATTN*HID, ww + ATTN, wb + 1, alphaS);
  k_agg1<<<(N_NODE*64)/256, 256, 0, stream>>>(startArr, relS, subS, alphaS,
        h16, re + (size_t)REL_VOCAB*HID, agg);
  k_node2<<<NB_NODE2, 256, 0, stream>>>(agg, h_t,
        Wh_t + 4096, Wih_t + 12288, Whh_t + 12288, bih + 3*HID, bhh + 3*HID,
        h_t, h16, wf, out, 1, 1);
}

// Round 6
// 476.305 us; speedup vs baseline: 12.3684x; 1.0607x over previous
//
#include <hip/hip_runtime.h>

#define N_NODE 100000
#define N_EDGE 1000000
#define HID 64
#define ATTN 32
#define REL_VOCAB 2005
#define SCAN_M (N_NODE + 1)
#define SCAN_NB ((SCAN_M + 1023) / 1024)

__device__ __forceinline__ float sigf(float x){ return 1.0f/(1.0f+__expf(-x)); }
__device__ __forceinline__ float bf2f(unsigned short u){
  return __uint_as_float(((unsigned int)u) << 16);
}
__device__ __forceinline__ unsigned short f2bf(float f){  // RNE
  unsigned int x = __float_as_uint(f);
  x += 0x7fffu + ((x >> 16) & 1u);
  return (unsigned short)(x >> 16);
}

__device__ __forceinline__ float dot64(const float4* a, const float4* __restrict__ w){
  float s0=0.f,s1=0.f,s2=0.f,s3=0.f;
  #pragma unroll
  for (int i=0;i<16;i++){
    float4 av=a[i]; float4 wv=w[i];
    s0=fmaf(av.x,wv.x,s0); s1=fmaf(av.y,wv.y,s1);
    s2=fmaf(av.z,wv.z,s2); s3=fmaf(av.w,wv.w,s3);
  }
  return (s0+s1)+(s2+s3);
}

// ---- per-relation precompute ----
__global__ void __launch_bounds__(256, 2) k_pre(
    const float* __restrict__ re, const float* __restrict__ Wr,
    const float* __restrict__ ww, const float* __restrict__ wb,
    float* __restrict__ scaledRel, float* __restrict__ hrW1)
{
  int r = blockIdx.x*blockDim.x + threadIdx.x;
  if (r >= REL_VOCAB) return;

  float4 e0[16];
  const float4* re0 = (const float4*)(re + r*HID);
  #pragma unroll
  for (int i=0;i<16;i++) e0[i]=re0[i];

  float acc = wb[0];
  #pragma unroll
  for (int j=0;j<ATTN;j++){
    float d = dot64(e0, (const float4*)(Wr + j*HID));
    d = fmaxf(d, 0.f);
    acc = fmaf(d, ww[j], acc);
  }
  float alpha = sigf(acc);

  float4* srl = (float4*)(scaledRel + r*HID);
  #pragma unroll
  for (int i=0;i<16;i++){
    float4 v=e0[i];
    v.x*=alpha; v.y*=alpha; v.z*=alpha; v.w*=alpha;
    srl[i]=v;
  }

  float4 e1[16];
  const float4* re1 = (const float4*)(re + (REL_VOCAB + r)*HID);
  #pragma unroll
  for (int i=0;i<16;i++) e1[i]=re1[i];
  #pragma unroll
  for (int j=0;j<ATTN;j++)
    hrW1[r*ATTN+j] = dot64(e1, (const float4*)(Wr + (ATTN+j)*HID));
}

__global__ void k_zero(float4* __restrict__ p, int n4){
  int i = blockIdx.x*blockDim.x + threadIdx.x;
  if (i < n4) p[i] = make_float4(0.f,0.f,0.f,0.f);
}

// ---- weight transpose: k-major layouts for the node-phase GEMM ----
__global__ void k_wt(const float* __restrict__ Wh, const float* __restrict__ Wih,
                     const float* __restrict__ Whh, float* __restrict__ Wh_t,
                     float* __restrict__ Wih_t, float* __restrict__ Whh_t)
{
  int tid = blockIdx.x*blockDim.x + threadIdx.x;
  if (tid >= 2*28672) return;
  int li = tid / 28672, r = tid % 28672;
  if (r < 4096){
    int k = r / 64, m = r % 64;
    Wh_t[li*4096 + k*64 + m] = Wh[li*4096 + m*64 + k];
  } else if (r < 16384){
    int q = r - 4096; int k = q / 192, gm = q % 192;
    Wih_t[li*12288 + k*192 + gm] = Wih[li*12288 + gm*64 + k];
  } else {
    int q = r - 16384; int k = q / 192, gm = q % 192;
    Whh_t[li*12288 + k*192 + gm] = Whh[li*12288 + gm*64 + k];
  }
}

// ---- counting sort of edges by obj ----
__global__ void k_hist(const int* __restrict__ edges, int* __restrict__ count){
  int e = blockIdx.x*blockDim.x + threadIdx.x;
  if (e >= N_EDGE) return;
  atomicAdd(&count[edges[e*6+5]], 1);
}

__global__ void k_scan1(const int* __restrict__ count, int* __restrict__ start,
                        int* __restrict__ bsum)
{
  __shared__ int s[1024];
  int tid = threadIdx.x;
  int i = blockIdx.x*1024 + tid;
  int v = (i < SCAN_M) ? count[i] : 0;
  s[tid] = v; __syncthreads();
  #pragma unroll
  for (int off=1; off<1024; off<<=1){
    int t = (tid>=off) ? s[tid-off] : 0;
    __syncthreads();
    s[tid] += t;
    __syncthreads();
  }
  if (i < SCAN_M) start[i] = s[tid] - v;
  if (tid == 1023) bsum[blockIdx.x] = s[1023];
}

__global__ void k_scan2(const int* __restrict__ bsum, int* __restrict__ boff){
  if (threadIdx.x == 0){
    int run = 0;
    for (int b=0;b<SCAN_NB;b++){ boff[b]=run; run+=bsum[b]; }
  }
}

__global__ void k_scan3(int* __restrict__ start, const int* __restrict__ boff,
                        int* __restrict__ cursor)
{
  int i = blockIdx.x*1024 + threadIdx.x;
  if (i >= SCAN_M) return;
  int v = start[i] + boff[blockIdx.x];
  start[i] = v;
  if (i < N_NODE) cursor[i] = v;
}

// scatter: write packed rel/sub in sorted-by-obj order
__global__ void k_scatter(const int* __restrict__ edges, int* __restrict__ cursor,
                          int* __restrict__ relS, int* __restrict__ subS)
{
  int e = blockIdx.x*blockDim.x + threadIdx.x;
  if (e >= N_EDGE) return;
  int obj = edges[e*6+5];
  int rel = edges[e*6+2];
  int sub = edges[e*6+4];
  int pos = atomicAdd(&cursor[obj], 1);
  relS[pos] = rel;
  subS[pos] = sub;
}

// ---- layer-0 aggregation: wave per node, lane k owns channel k ----
__global__ void k_agg0(const int* __restrict__ startArr, const int* __restrict__ relS,
                       const float* __restrict__ scaledRel, float* __restrict__ agg)
{
  int t = blockIdx.x*blockDim.x + threadIdx.x;
  int n = __builtin_amdgcn_readfirstlane(t >> 6);
  int k = t & 63;
  if (n >= N_NODE) return;
  int b = startArr[n], e_ = startArr[n+1];
  float acc = 0.f;
  int i = b;
  for (; i+3 < e_; i += 4){
    int r0=relS[i], r1=relS[i+1], r2=relS[i+2], r3=relS[i+3];
    float v0=scaledRel[r0*HID+k], v1=scaledRel[r1*HID+k];
    float v2=scaledRel[r2*HID+k], v3=scaledRel[r3*HID+k];
    acc += v0; acc += v1; acc += v2; acc += v3;
  }
  for (; i < e_; ++i) acc += scaledRel[relS[i]*HID + k];
  agg[(size_t)n*HID + k] = acc;
}

// ---- layer-1 per-edge alpha (sorted order; bf16 h gather) ----
__global__ void __launch_bounds__(256, 2) k_alpha(
    const int* __restrict__ relS, const int* __restrict__ subS,
    const unsigned short* __restrict__ h16,
    const float* __restrict__ hrW1, const float* __restrict__ Ws1,
    const float* __restrict__ ww1, const float* __restrict__ wb1,
    float* __restrict__ alphaS)
{
  int i = blockIdx.x*blockDim.x + threadIdx.x;
  if (i >= N_EDGE) return;
  int sub = subS[i];
  int rel = relS[i];

  float hs[HID];
  const uint4* hp = (const uint4*)(h16 + (size_t)sub*HID);
  #pragma unroll
  for (int q=0;q<8;q++){
    uint4 u = hp[q];
    hs[q*8+0]=__uint_as_float(u.x<<16); hs[q*8+1]=__uint_as_float(u.x&0xffff0000u);
    hs[q*8+2]=__uint_as_float(u.y<<16); hs[q*8+3]=__uint_as_float(u.y&0xffff0000u);
    hs[q*8+4]=__uint_as_float(u.z<<16); hs[q*8+5]=__uint_as_float(u.z&0xffff0000u);
    hs[q*8+6]=__uint_as_float(u.w<<16); hs[q*8+7]=__uint_as_float(u.w&0xffff0000u);
  }

  const float* hw = hrW1 + rel*ATTN;
  float acc = wb1[0];
  #pragma unroll
  for (int j=0;j<ATTN;j++){
    float aj = hw[j];
    const float* wr = Ws1 + j*HID;   // uniform -> scalar loads
    #pragma unroll
    for (int k=0;k<HID;k++) aj = fmaf(hs[k], wr[k], aj);
    acc = fmaf(fmaxf(aj, 0.f), ww1[j], acc);
  }
  alphaS[i] = sigf(acc);
}

// ---- layer-1 aggregation: wave per node; bf16 h gather; 2-deep ILP ----
__global__ void k_agg1(const int* __restrict__ startArr, const int* __restrict__ relS,
                       const int* __restrict__ subS, const float* __restrict__ alphaS,
                       const unsigned short* __restrict__ h16,
                       const float* __restrict__ re1, float* __restrict__ agg)
{
  int t = blockIdx.x*blockDim.x + threadIdx.x;
  int n = __builtin_amdgcn_readfirstlane(t >> 6);
  int k = t & 63;
  if (n >= N_NODE) return;
  int b = startArr[n], e_ = startArr[n+1];
  float acc = 0.f;
  int i = b;
  for (; i+1 < e_; i += 2){
    int r0 = relS[i],   s0 = subS[i];
    int r1 = relS[i+1], s1 = subS[i+1];
    float al0 = alphaS[i], al1 = alphaS[i+1];
    float h0 = bf2f(h16[(size_t)s0*HID + k]);
    float h1 = bf2f(h16[(size_t)s1*HID + k]);
    float v0 = re1[r0*HID + k];
    float v1 = re1[r1*HID + k];
    acc = fmaf(al0, h0 + v0, acc);
    acc = fmaf(al1, h1 + v1, acc);
  }
  if (i < e_){
    int r0 = relS[i], s0 = subS[i];
    acc = fmaf(alphaS[i], bf2f(h16[(size_t)s0*HID + k]) + re1[r0*HID + k], acc);
  }
  agg[(size_t)n*HID + k] = acc;
}

// ---- fused node phase (64-node tile, 256 threads) ----
// sA is union'd: holds agg^T in phases 1-2, x^T in phase 3, score-reduction
// scratch in mode-1 epilogue. sh only exists for HAS_H0=1 (layer-1) -> layer-0
// LDS is 16.9 KB (high occupancy). Rows padded to 65 floats + scalar staging
// writes: all LDS access conflict-free.
template<int HAS_H0>
__global__ void __launch_bounds__(256, 4) k_node2(
    const float* __restrict__ agg, const float* __restrict__ h_t_prev,
    const float* __restrict__ Wh_t, const float* __restrict__ Wih_t,
    const float* __restrict__ Whh_t, const float* __restrict__ bih,
    const float* __restrict__ bhh,
    float* __restrict__ h_t_out, unsigned short* __restrict__ h16_out,
    const float* __restrict__ wf, float* __restrict__ score,
    int mode)
{
  __shared__ float sA[HID][65];                    // agg^T, then x^T
  __shared__ float sh[HAS_H0 ? HID : 1][65];       // h0^T (layer 1 only)

  const int t = threadIdx.x;
  const int n0 = blockIdx.x * 64;

  // ---- phase 1: staging ----
  {
    const int nr = t >> 2;
    const int kc = (t & 3) * 16;
    const int nn = n0 + nr;
    float va[16];
    if (nn < N_NODE){
      const float4* ap = (const float4*)(agg + (size_t)nn*HID + kc);
      float4 a0=ap[0], a1=ap[1], a2=ap[2], a3=ap[3];
      va[0]=a0.x; va[1]=a0.y; va[2]=a0.z; va[3]=a0.w;
      va[4]=a1.x; va[5]=a1.y; va[6]=a1.z; va[7]=a1.w;
      va[8]=a2.x; va[9]=a2.y; va[10]=a2.z; va[11]=a2.w;
      va[12]=a3.x; va[13]=a3.y; va[14]=a3.z; va[15]=a3.w;
    } else {
      #pragma unroll
      for (int j=0;j<16;j++) va[j]=0.f;
    }
    #pragma unroll
    for (int j=0;j<16;j++) sA[kc+j][nr] = va[j];

    if (HAS_H0){
      // h_t_prev k-major [64][N_NODE]; coalesced read (<=16-float tail
      // overread stays inside workspace; OOB-node values never used)
      const float4* hp = (const float4*)(h_t_prev + (size_t)nr*N_NODE + n0 + kc);
      float4 b0=hp[0], b1=hp[1], b2=hp[2], b3=hp[3];
      sh[nr][kc+0]=b0.x;  sh[nr][kc+1]=b0.y;  sh[nr][kc+2]=b0.z;  sh[nr][kc+3]=b0.w;
      sh[nr][kc+4]=b1.x;  sh[nr][kc+5]=b1.y;  sh[nr][kc+6]=b1.z;  sh[nr][kc+7]=b1.w;
      sh[nr][kc+8]=b2.x;  sh[nr][kc+9]=b2.y;  sh[nr][kc+10]=b2.z; sh[nr][kc+11]=b2.w;
      sh[nr][kc+12]=b3.x; sh[nr][kc+13]=b3.y; sh[nr][kc+14]=b3.z; sh[nr][kc+15]=b3.w;
    }
  }
  __syncthreads();

  const int l  = t & 63;
  const int m0 = __builtin_amdgcn_readfirstlane((t >> 6) * 16);

  // ---- phase 2: x = relu(agg @ Wh^T) ----
  float xa[16];
  #pragma unroll
  for (int c=0;c<16;c++) xa[c]=0.f;
  for (int k=0;k<HID;k++){
    float av = sA[k][l];
    const float* wt = Wh_t + k*HID + m0;
    #pragma unroll
    for (int c=0;c<16;c++) xa[c] = fmaf(av, wt[c], xa[c]);
  }
  __syncthreads();            // all sagg reads complete
  #pragma unroll
  for (int c=0;c<16;c++) sA[m0+c][l] = fmaxf(xa[c], 0.f);
  __syncthreads();            // x^T visible

  // ---- phase 3: GRU gate GEMMs ----
  float air[16],aiz[16],ain[16],ahr[16],ahz[16],ahn[16];
  #pragma unroll
  for (int c=0;c<16;c++){ air[c]=0.f; aiz[c]=0.f; ain[c]=0.f;
                          ahr[c]=0.f; ahz[c]=0.f; ahn[c]=0.f; }
  if (HAS_H0){
    for (int k=0;k<HID;k++){
      float xv = sA[k][l];
      float hv = sh[k][l];
      const float* wi = Wih_t + k*192 + m0;
      const float* wh = Whh_t + k*192 + m0;
      #pragma unroll
      for (int c=0;c<16;c++){
        air[c] = fmaf(xv, wi[c],     air[c]);
        aiz[c] = fmaf(xv, wi[64+c],  aiz[c]);
        ain[c] = fmaf(xv, wi[128+c], ain[c]);
      }
      #pragma unroll
      for (int c=0;c<16;c++){
        ahr[c] = fmaf(hv, wh[c],     ahr[c]);
        ahz[c] = fmaf(hv, wh[64+c],  ahz[c]);
        ahn[c] = fmaf(hv, wh[128+c], ahn[c]);
      }
    }
  } else {
    for (int k=0;k<HID;k++){
      float xv = sA[k][l];
      const float* wi = Wih_t + k*192 + m0;
      #pragma unroll
      for (int c=0;c<16;c++){
        air[c] = fmaf(xv, wi[c],     air[c]);
        aiz[c] = fmaf(xv, wi[64+c],  aiz[c]);
        ain[c] = fmaf(xv, wi[128+c], ain[c]);
      }
    }
  }

  // ---- GRU epilogue ----
  float ov[16];
  #pragma unroll
  for (int c=0;c<16;c++){
    int m = m0 + c;
    float gir = air[c] + bih[m];
    float giz = aiz[c] + bih[64+m];
    float gin = ain[c] + bih[128+m];
    float ghr = bhh[m], ghz = bhh[64+m], ghn = bhh[128+m];
    if (HAS_H0){ ghr += ahr[c]; ghz += ahz[c]; ghn += ahn[c]; }
    float r  = sigf(gir + ghr);
    float z  = sigf(giz + ghz);
    float nn = tanhf(fmaf(r, ghn, gin));
    float h0v = HAS_H0 ? sh[m0+c][l] : 0.f;
    ov[c] = (1.f - z)*nn + z*h0v;
  }

  const int n = n0 + l;
  if (mode == 1){
    // fused score = h @ W_final, reduced across the 4 waves via LDS
    float part = 0.f;
    #pragma unroll
    for (int c=0;c<16;c++) part = fmaf(ov[c], wf[m0+c], part);
    __syncthreads();                    // all sA (x^T) reads complete
    float* red = &sA[0][0];
    red[(t>>6)*64 + l] = part;
    __syncthreads();
    if (t < 64){
      int nn2 = n0 + t;
      if (nn2 < N_NODE)
        score[nn2] = (red[t] + red[64+t]) + (red[128+t] + red[192+t]);
    }
  } else {
    if (n < N_NODE){
      #pragma unroll
      for (int c=0;c<16;c++)
        h_t_out[(size_t)(m0+c)*N_NODE + n] = ov[c];
      unsigned int p[8];
      #pragma unroll
      for (int q=0;q<8;q++){
        unsigned int lo = f2bf(ov[2*q]);
        unsigned int hi = f2bf(ov[2*q+1]);
        p[q] = lo | (hi << 16);
      }
      uint4* hp16 = (uint4*)(h16_out + (size_t)n*HID + m0);
      hp16[0] = make_uint4(p[0],p[1],p[2],p[3]);
      hp16[1] = make_uint4(p[4],p[5],p[6],p[7]);
    }
  }
}

extern "C" void kernel_launch(void* const* d_in, const int* in_sizes, int n_in,
                              void* d_out, int out_size, void* d_ws, size_t ws_size,
                              hipStream_t stream)
{
  const int*   edges = (const int*)  d_in[0];
  const float* re    = (const float*)d_in[1];
  const float* Ws    = (const float*)d_in[2];
  const float* Wr    = (const float*)d_in[3];
  const float* ww    = (const float*)d_in[4];
  const float* wb    = (const float*)d_in[5];
  const float* Wh    = (const float*)d_in[6];
  const float* Wih   = (const float*)d_in[7];
  const float* Whh   = (const float*)d_in[8];
  const float* bih   = (const float*)d_in[9];
  const float* bhh   = (const float*)d_in[10];
  const float* wf    = (const float*)d_in[11];
  float* out = (float*)d_out;

  // workspace layout (floats unless noted)
  float* agg       = (float*)d_ws;                       // 6,400,000
  float* h_t       = agg + (size_t)N_NODE*HID;           // 6,400,000 (k-major)
  unsigned short* h16 = (unsigned short*)(h_t + (size_t)N_NODE*HID); // 6,400,000 u16
  float* scaledRel = (float*)(h16 + (size_t)N_NODE*HID); // 128,320
  float* hrW1      = scaledRel + REL_VOCAB*HID;          // 64,160
  float* alphaS    = hrW1 + REL_VOCAB*ATTN;              // 1,000,000
  float* Wh_t      = alphaS + N_EDGE;                    // 8,192
  float* Wih_t     = Wh_t + 2*4096;                      // 24,576
  float* Whh_t     = Wih_t + 2*12288;                    // 24,576
  int*   count     = (int*)(Whh_t + 2*12288);            // 100,004
  int*   startArr  = count + 100004;                     // 100,004
  int*   cursor    = startArr + 100004;                  // 100,004
  int*   bsum      = cursor + 100004;                    // 128
  int*   boff      = bsum + 128;                         // 128
  int*   relS      = boff + 128;                         // 1,000,000
  int*   subS      = relS + N_EDGE;                      // 1,000,000

  // ---- counting sort of edges by obj (packed rel/sub) ----
  k_zero<<<(100004/4+255)/256, 256, 0, stream>>>((float4*)count, 100004/4);
  k_hist<<<(N_EDGE+255)/256, 256, 0, stream>>>(edges, count);
  k_scan1<<<SCAN_NB, 1024, 0, stream>>>(count, startArr, bsum);
  k_scan2<<<1, 64, 0, stream>>>(bsum, boff);
  k_scan3<<<SCAN_NB, 1024, 0, stream>>>(startArr, boff, cursor);
  k_scatter<<<(N_EDGE+255)/256, 256, 0, stream>>>(edges, cursor, relS, subS);

  // ---- per-relation tables + weight transposes ----
  k_pre<<<(REL_VOCAB+255)/256, 256, 0, stream>>>(re, Wr, ww, wb, scaledRel, hrW1);
  k_wt<<<(2*28672+255)/256, 256, 0, stream>>>(Wh, Wih, Whh, Wh_t, Wih_t, Whh_t);

  const int NB_NODE2 = (N_NODE + 63) / 64;

  // ---- layer 0 ----
  k_agg0<<<(N_NODE*64)/256, 256, 0, stream>>>(startArr, relS, scaledRel, agg);
  k_node2<0><<<NB_NODE2, 256, 0, stream>>>(agg, h_t,
        Wh_t, Wih_t, Whh_t, bih, bhh, h_t, h16, wf, out, 0);

  // ---- layer 1 ----
  k_alpha<<<(N_EDGE+255)/256, 256, 0, stream>>>(relS, subS, h16, hrW1,
        Ws + ATTN*HID, ww + ATTN, wb + 1, alphaS);
  k_agg1<<<(N_NODE*64)/256, 256, 0, stream>>>(startArr, relS, subS, alphaS,
        h16, re + (size_t)REL_VOCAB*HID, agg);
  k_node2<1><<<NB_NODE2, 256, 0, stream>>>(agg, h_t,
        Wh_t + 4096, Wih_t + 12288, Whh_t + 12288, bih + 3*HID, bhh + 3*HID,
        h_t, h16, wf, out, 1);
}

// Round 7
// 373.007 us; speedup vs baseline: 15.7936x; 1.2769x over previous
//
#include <hip/hip_runtime.h>

#define N_NODE 100000
#define N_PAD  100064            // padded rows for OOB-safe fragment loads
#define N_EDGE 1000000
#define HID 64
#define ATTN 32
#define REL_VOCAB 2005
#define SCAN_M (N_NODE + 1)
#define SCAN_NB ((SCAN_M + 1023) / 1024)

typedef short  bf16x8 __attribute__((ext_vector_type(8)));
typedef float  f32x4  __attribute__((ext_vector_type(4)));

__device__ __forceinline__ float sigf(float x){ return 1.0f/(1.0f+__expf(-x)); }
__device__ __forceinline__ float bf2f(unsigned short u){
  return __uint_as_float(((unsigned int)u) << 16);
}
__device__ __forceinline__ unsigned short f2bf(float f){  // RNE
  unsigned int x = __float_as_uint(f);
  x += 0x7fffu + ((x >> 16) & 1u);
  return (unsigned short)(x >> 16);
}

__device__ __forceinline__ float dot64(const float4* a, const float4* __restrict__ w){
  float s0=0.f,s1=0.f,s2=0.f,s3=0.f;
  #pragma unroll
  for (int i=0;i<16;i++){
    float4 av=a[i]; float4 wv=w[i];
    s0=fmaf(av.x,wv.x,s0); s1=fmaf(av.y,wv.y,s1);
    s2=fmaf(av.z,wv.z,s2); s3=fmaf(av.w,wv.w,s3);
  }
  return (s0+s1)+(s2+s3);
}

// ---- per-relation precompute ----
__global__ void __launch_bounds__(256, 2) k_pre(
    const float* __restrict__ re, const float* __restrict__ Wr,
    const float* __restrict__ ww, const float* __restrict__ wb,
    float* __restrict__ scaledRel, float* __restrict__ hrW1)
{
  int r = blockIdx.x*blockDim.x + threadIdx.x;
  if (r >= REL_VOCAB) return;

  float4 e0[16];
  const float4* re0 = (const float4*)(re + r*HID);
  #pragma unroll
  for (int i=0;i<16;i++) e0[i]=re0[i];

  float acc = wb[0];
  #pragma unroll
  for (int j=0;j<ATTN;j++){
    float d = dot64(e0, (const float4*)(Wr + j*HID));
    d = fmaxf(d, 0.f);
    acc = fmaf(d, ww[j], acc);
  }
  float alpha = sigf(acc);

  float4* srl = (float4*)(scaledRel + r*HID);
  #pragma unroll
  for (int i=0;i<16;i++){
    float4 v=e0[i];
    v.x*=alpha; v.y*=alpha; v.z*=alpha; v.w*=alpha;
    srl[i]=v;
  }

  float4 e1[16];
  const float4* re1 = (const float4*)(re + (REL_VOCAB + r)*HID);
  #pragma unroll
  for (int i=0;i<16;i++) e1[i]=re1[i];
  #pragma unroll
  for (int j=0;j<ATTN;j++)
    hrW1[r*ATTN+j] = dot64(e1, (const float4*)(Wr + (ATTN+j)*HID));
}

__global__ void k_zero(float4* __restrict__ p, int n4){
  int i = blockIdx.x*blockDim.x + threadIdx.x;
  if (i < n4) p[i] = make_float4(0.f,0.f,0.f,0.f);
}

// ---- weight pack: bf16 MFMA B-fragment order ----
// record(nt, c, lane): 8 bf16 = W[nt*16 + (lane&15)][c*32 + (lane>>4)*8 + j]
// (W is the fp32 row-major [outchan][k] matrix; B-operand = W^T[k][outchan])
__global__ void k_wt(const float* __restrict__ Wh, const float* __restrict__ Wih,
                     const float* __restrict__ Whh, unsigned short* __restrict__ pkWh,
                     unsigned short* __restrict__ pkWih, unsigned short* __restrict__ pkWhh)
{
  int tid = blockIdx.x*blockDim.x + threadIdx.x;
  if (tid >= 2*3584) return;
  int li = tid / 3584, e = tid % 3584;
  const float* src; unsigned short* dst; int nt, c, l;
  if (e < 512){                       // Wh: 4 tiles x 2 chunks x 64 lanes
    nt = e >> 7; c = (e>>6)&1; l = e&63;
    src = Wh + li*4096;
    dst = pkWh + (size_t)((li*8 + nt*2 + c)*64 + l)*8;
  } else if (e < 2048){               // Wih: 12 tiles
    int q = e - 512; nt = q >> 7; c = (q>>6)&1; l = q&63;
    src = Wih + li*12288;
    dst = pkWih + (size_t)((li*24 + nt*2 + c)*64 + l)*8;
  } else {                            // Whh: 12 tiles
    int q = e - 2048; nt = q >> 7; c = (q>>6)&1; l = q&63;
    src = Whh + li*12288;
    dst = pkWhh + (size_t)((li*24 + nt*2 + c)*64 + l)*8;
  }
  int row = nt*16 + (l&15);
  int k0  = c*32 + (l>>4)*8;
  #pragma unroll
  for (int j=0;j<8;j++) dst[j] = f2bf(src[row*64 + k0 + j]);
}

// ---- counting sort of edges by obj ----
__global__ void k_hist(const int* __restrict__ edges, int* __restrict__ count){
  int e = blockIdx.x*blockDim.x + threadIdx.x;
  if (e >= N_EDGE) return;
  atomicAdd(&count[edges[e*6+5]], 1);
}

__global__ void k_scan1(const int* __restrict__ count, int* __restrict__ start,
                        int* __restrict__ bsum)
{
  __shared__ int s[1024];
  int tid = threadIdx.x;
  int i = blockIdx.x*1024 + tid;
  int v = (i < SCAN_M) ? count[i] : 0;
  s[tid] = v; __syncthreads();
  #pragma unroll
  for (int off=1; off<1024; off<<=1){
    int t = (tid>=off) ? s[tid-off] : 0;
    __syncthreads();
    s[tid] += t;
    __syncthreads();
  }
  if (i < SCAN_M) start[i] = s[tid] - v;
  if (tid == 1023) bsum[blockIdx.x] = s[1023];
}

__global__ void k_scan2(const int* __restrict__ bsum, int* __restrict__ boff){
  if (threadIdx.x == 0){
    int run = 0;
    for (int b=0;b<SCAN_NB;b++){ boff[b]=run; run+=bsum[b]; }
  }
}

__global__ void k_scan3(int* __restrict__ start, const int* __restrict__ boff,
                        int* __restrict__ cursor)
{
  int i = blockIdx.x*1024 + threadIdx.x;
  if (i >= SCAN_M) return;
  int v = start[i] + boff[blockIdx.x];
  start[i] = v;
  if (i < N_NODE) cursor[i] = v;
}

__global__ void k_scatter(const int* __restrict__ edges, int* __restrict__ cursor,
                          int* __restrict__ relS, int* __restrict__ subS)
{
  int e = blockIdx.x*blockDim.x + threadIdx.x;
  if (e >= N_EDGE) return;
  int obj = edges[e*6+5];
  int rel = edges[e*6+2];
  int sub = edges[e*6+4];
  int pos = atomicAdd(&cursor[obj], 1);
  relS[pos] = rel;
  subS[pos] = sub;
}

// ---- layer-0 aggregation: wave per node -> bf16 agg ----
__global__ void k_agg0(const int* __restrict__ startArr, const int* __restrict__ relS,
                       const float* __restrict__ scaledRel, unsigned short* __restrict__ agg16)
{
  int t = blockIdx.x*blockDim.x + threadIdx.x;
  int n = __builtin_amdgcn_readfirstlane(t >> 6);
  int k = t & 63;
  if (n >= N_NODE) return;
  int b = startArr[n], e_ = startArr[n+1];
  float acc = 0.f;
  int i = b;
  for (; i+3 < e_; i += 4){
    int r0=relS[i], r1=relS[i+1], r2=relS[i+2], r3=relS[i+3];
    float v0=scaledRel[r0*HID+k], v1=scaledRel[r1*HID+k];
    float v2=scaledRel[r2*HID+k], v3=scaledRel[r3*HID+k];
    acc += v0; acc += v1; acc += v2; acc += v3;
  }
  for (; i < e_; ++i) acc += scaledRel[relS[i]*HID + k];
  agg16[(size_t)n*HID + k] = f2bf(acc);
}

// ---- layer-1 per-edge alpha (sorted order; bf16 h gather) ----
__global__ void __launch_bounds__(256, 2) k_alpha(
    const int* __restrict__ relS, const int* __restrict__ subS,
    const unsigned short* __restrict__ h16,
    const float* __restrict__ hrW1, const float* __restrict__ Ws1,
    const float* __restrict__ ww1, const float* __restrict__ wb1,
    float* __restrict__ alphaS)
{
  int i = blockIdx.x*blockDim.x + threadIdx.x;
  if (i >= N_EDGE) return;
  int sub = subS[i];
  int rel = relS[i];

  float hs[HID];
  const uint4* hp = (const uint4*)(h16 + (size_t)sub*HID);
  #pragma unroll
  for (int q=0;q<8;q++){
    uint4 u = hp[q];
    hs[q*8+0]=__uint_as_float(u.x<<16); hs[q*8+1]=__uint_as_float(u.x&0xffff0000u);
    hs[q*8+2]=__uint_as_float(u.y<<16); hs[q*8+3]=__uint_as_float(u.y&0xffff0000u);
    hs[q*8+4]=__uint_as_float(u.z<<16); hs[q*8+5]=__uint_as_float(u.z&0xffff0000u);
    hs[q*8+6]=__uint_as_float(u.w<<16); hs[q*8+7]=__uint_as_float(u.w&0xffff0000u);
  }

  const float* hw = hrW1 + rel*ATTN;
  float acc = wb1[0];
  #pragma unroll
  for (int j=0;j<ATTN;j++){
    float aj = hw[j];
    const float* wr = Ws1 + j*HID;   // uniform -> scalar loads
    #pragma unroll
    for (int k=0;k<HID;k++) aj = fmaf(hs[k], wr[k], aj);
    acc = fmaf(fmaxf(aj, 0.f), ww1[j], acc);
  }
  alphaS[i] = sigf(acc);
}

// ---- layer-1 aggregation: wave per node; bf16 h gather -> bf16 agg ----
__global__ void k_agg1(const int* __restrict__ startArr, const int* __restrict__ relS,
                       const int* __restrict__ subS, const float* __restrict__ alphaS,
                       const unsigned short* __restrict__ h16,
                       const float* __restrict__ re1, unsigned short* __restrict__ agg16)
{
  int t = blockIdx.x*blockDim.x + threadIdx.x;
  int n = __builtin_amdgcn_readfirstlane(t >> 6);
  int k = t & 63;
  if (n >= N_NODE) return;
  int b = startArr[n], e_ = startArr[n+1];
  float acc = 0.f;
  int i = b;
  for (; i+1 < e_; i += 2){
    int r0 = relS[i],   s0 = subS[i];
    int r1 = relS[i+1], s1 = subS[i+1];
    float al0 = alphaS[i], al1 = alphaS[i+1];
    float h0 = bf2f(h16[(size_t)s0*HID + k]);
    float h1 = bf2f(h16[(size_t)s1*HID + k]);
    float v0 = re1[r0*HID + k];
    float v1 = re1[r1*HID + k];
    acc = fmaf(al0, h0 + v0, acc);
    acc = fmaf(al1, h1 + v1, acc);
  }
  if (i < e_){
    int r0 = relS[i], s0 = subS[i];
    acc = fmaf(alphaS[i], bf2f(h16[(size_t)s0*HID + k]) + re1[r0*HID + k], acc);
  }
  agg16[(size_t)n*HID + k] = f2bf(acc);
}

// ---- MFMA node phase: 64 nodes/block, wave w owns nodes w*16..w*16+15 ----
// A-frags (agg, h0) load straight from row-major bf16 tables; B-frags from
// pre-packed weights (one coalesced 16B load/lane, L1-resident). X transits an
// XOR-swizzled LDS tile (stride-128B rows would otherwise be 16-way conflicts).
// Gate GEMMs run as 3 passes (r,z,n) to bound C-frag register pressure.
// mode 0: write h16.  mode 1: fused score = h @ wf (shfl-xor reduce).
template<int HAS_H0>
__global__ void __launch_bounds__(256, 2) k_node2(
    const unsigned short* __restrict__ agg16,
    const unsigned short* __restrict__ h16,
    const unsigned short* __restrict__ pkWh,
    const unsigned short* __restrict__ pkWih,
    const unsigned short* __restrict__ pkWhh,
    const float* __restrict__ bih, const float* __restrict__ bhh,
    unsigned short* __restrict__ h16_out,
    const float* __restrict__ wf, float* __restrict__ score, int mode)
{
  __shared__ unsigned short xlds[4096];   // 4 waves x [16 rows][64 cols] bf16, swizzled

  const int t  = threadIdx.x;
  const int w  = t >> 6, l = t & 63;
  const int lr = l & 15;                  // fragment row/col
  const int lg = l >> 4;                  // k-group
  const int n0 = blockIdx.x * 64;
  const int rowA = n0 + w*16 + lr;

  // A-fragments from global bf16 tables (rows padded to N_PAD; OOB rows junk, discarded)
  bf16x8 aA0 = *(const bf16x8*)(agg16 + (size_t)rowA*HID + lg*8);
  bf16x8 aA1 = *(const bf16x8*)(agg16 + (size_t)rowA*HID + 32 + lg*8);
  bf16x8 hA0, hA1;
  if (HAS_H0){
    hA0 = *(const bf16x8*)(h16 + (size_t)rowA*HID + lg*8);
    hA1 = *(const bf16x8*)(h16 + (size_t)rowA*HID + 32 + lg*8);
  }

  // biases + wf (per-lane channel nt*16+lr; L1-resident)
  float bir[4],biz[4],bin[4],bhr[4],bhz[4],bhn[4],wfv[4];
  #pragma unroll
  for (int nt=0;nt<4;nt++){
    int ch = nt*16 + lr;
    bir[nt]=bih[ch]; biz[nt]=bih[64+ch]; bin[nt]=bih[128+ch];
    bhr[nt]=bhh[ch]; bhz[nt]=bhh[64+ch]; bhn[nt]=bhh[128+ch];
    wfv[nt]=wf[ch];
  }

  // ---- X = relu(agg @ Wh^T) ----
  #pragma unroll
  for (int nt=0;nt<4;nt++){
    f32x4 acc = {0.f,0.f,0.f,0.f};
    bf16x8 b0 = *(const bf16x8*)(pkWh + (size_t)((nt*2+0)*64 + l)*8);
    bf16x8 b1 = *(const bf16x8*)(pkWh + (size_t)((nt*2+1)*64 + l)*8);
    acc = __builtin_amdgcn_mfma_f32_16x16x32_bf16(aA0, b0, acc, 0,0,0);
    acc = __builtin_amdgcn_mfma_f32_16x16x32_bf16(aA1, b1, acc, 0,0,0);
    #pragma unroll
    for (int r=0;r<4;r++){
      int m = lg*4 + r, col = nt*16 + lr;
      xlds[w*1024 + m*64 + (col ^ ((m&7)<<3))] = f2bf(fmaxf(acc[r], 0.f));
    }
  }
  __syncthreads();

  // X A-fragments from swizzled LDS
  const int xbase = w*1024 + lr*64;
  const int sw = (lr&7)<<3;
  bf16x8 xA0 = *(const bf16x8*)&xlds[xbase + ((lg*8)      ^ sw)];
  bf16x8 xA1 = *(const bf16x8*)&xlds[xbase + ((32 + lg*8) ^ sw)];

  // ---- gate passes ----
  float rv[16], zv[16], hv[16];
  #pragma unroll
  for (int g=0; g<2; ++g){               // g=0: r-gate, g=1: z-gate
    #pragma unroll
    for (int nt=0;nt<4;nt++){
      int gt = g*4 + nt;
      f32x4 ai = {0.f,0.f,0.f,0.f};
      bf16x8 bi0 = *(const bf16x8*)(pkWih + (size_t)((gt*2+0)*64 + l)*8);
      bf16x8 bi1 = *(const bf16x8*)(pkWih + (size_t)((gt*2+1)*64 + l)*8);
      ai = __builtin_amdgcn_mfma_f32_16x16x32_bf16(xA0, bi0, ai, 0,0,0);
      ai = __builtin_amdgcn_mfma_f32_16x16x32_bf16(xA1, bi1, ai, 0,0,0);
      f32x4 ah = {0.f,0.f,0.f,0.f};
      if (HAS_H0){
        bf16x8 bh0 = *(const bf16x8*)(pkWhh + (size_t)((gt*2+0)*64 + l)*8);
        bf16x8 bh1 = *(const bf16x8*)(pkWhh + (size_t)((gt*2+1)*64 + l)*8);
        ah = __builtin_amdgcn_mfma_f32_16x16x32_bf16(hA0, bh0, ah, 0,0,0);
        ah = __builtin_amdgcn_mfma_f32_16x16x32_bf16(hA1, bh1, ah, 0,0,0);
      }
      #pragma unroll
      for (int r=0;r<4;r++){
        float bi_ = (g==0) ? bir[nt] : biz[nt];
        float bh_ = (g==0) ? bhr[nt] : bhz[nt];
        float v = sigf(ai[r] + bi_ + ah[r] + bh_);
        if (g==0) rv[nt*4+r] = v; else zv[nt*4+r] = v;
      }
    }
  }
  #pragma unroll
  for (int nt=0;nt<4;nt++){              // n-gate + GRU blend
    int gt = 8 + nt;
    f32x4 ai = {0.f,0.f,0.f,0.f};
    bf16x8 bi0 = *(const bf16x8*)(pkWih + (size_t)((gt*2+0)*64 + l)*8);
    bf16x8 bi1 = *(const bf16x8*)(pkWih + (size_t)((gt*2+1)*64 + l)*8);
    ai = __builtin_amdgcn_mfma_f32_16x16x32_bf16(xA0, bi0, ai, 0,0,0);
    ai = __builtin_amdgcn_mfma_f32_16x16x32_bf16(xA1, bi1, ai, 0,0,0);
    f32x4 ah = {0.f,0.f,0.f,0.f};
    if (HAS_H0){
      bf16x8 bh0 = *(const bf16x8*)(pkWhh + (size_t)((gt*2+0)*64 + l)*8);
      bf16x8 bh1 = *(const bf16x8*)(pkWhh + (size_t)((gt*2+1)*64 + l)*8);
      ah = __builtin_amdgcn_mfma_f32_16x16x32_bf16(hA0, bh0, ah, 0,0,0);
      ah = __builtin_amdgcn_mfma_f32_16x16x32_bf16(hA1, bh1, ah, 0,0,0);
    }
    #pragma unroll
    for (int r=0;r<4;r++){
      float gin = ai[r] + bin[nt];
      float ghn = ah[r] + bhn[nt];
      float rr  = rv[nt*4+r];
      float nn  = tanhf(fmaf(rr, ghn, gin));
      float z   = zv[nt*4+r];
      float h0v = 0.f;
      if (HAS_H0)
        h0v = bf2f(h16[(size_t)(n0 + w*16 + lg*4 + r)*HID + nt*16 + lr]);
      hv[nt*4+r] = (1.f - z)*nn + z*h0v;
    }
  }

  if (mode == 0){
    // transpose h through (now free) xlds, then coalesced bf16x8 stores
    __syncthreads();
    #pragma unroll
    for (int nt=0;nt<4;nt++)
      #pragma unroll
      for (int r=0;r<4;r++){
        int m = lg*4 + r, col = nt*16 + lr;
        xlds[w*1024 + m*64 + (col ^ ((m&7)<<3))] = f2bf(hv[nt*4+r]);
      }
    __syncthreads();
    int rr2 = l >> 2, cc = l & 3;
    int n = n0 + w*16 + rr2;
    if (n < N_NODE){
      int base = w*1024 + rr2*64, s2 = (rr2&7)<<3;
      bf16x8 v0 = *(const bf16x8*)&xlds[base + ((cc*16)     ^ s2)];
      bf16x8 v1 = *(const bf16x8*)&xlds[base + ((cc*16 + 8) ^ s2)];
      *(bf16x8*)(h16_out + (size_t)n*HID + cc*16)     = v0;
      *(bf16x8*)(h16_out + (size_t)n*HID + cc*16 + 8) = v1;
    }
  } else {
    // fused score = h @ wf; reduce the 16 channel-lanes per node
    #pragma unroll
    for (int r=0;r<4;r++){
      float p = 0.f;
      #pragma unroll
      for (int nt=0;nt<4;nt++) p = fmaf(hv[nt*4+r], wfv[nt], p);
      p += __shfl_xor(p, 1);
      p += __shfl_xor(p, 2);
      p += __shfl_xor(p, 4);
      p += __shfl_xor(p, 8);
      if (lr == 0){
        int n = n0 + w*16 + lg*4 + r;
        if (n < N_NODE) score[n] = p;
      }
    }
  }
}

extern "C" void kernel_launch(void* const* d_in, const int* in_sizes, int n_in,
                              void* d_out, int out_size, void* d_ws, size_t ws_size,
                              hipStream_t stream)
{
  const int*   edges = (const int*)  d_in[0];
  const float* re    = (const float*)d_in[1];
  const float* Ws    = (const float*)d_in[2];
  const float* Wr    = (const float*)d_in[3];
  const float* ww    = (const float*)d_in[4];
  const float* wb    = (const float*)d_in[5];
  const float* Wh    = (const float*)d_in[6];
  const float* Wih   = (const float*)d_in[7];
  const float* Whh   = (const float*)d_in[8];
  const float* bih   = (const float*)d_in[9];
  const float* bhh   = (const float*)d_in[10];
  const float* wf    = (const float*)d_in[11];
  float* out = (float*)d_out;

  // workspace layout
  unsigned short* agg16 = (unsigned short*)d_ws;               // N_PAD*HID u16
  unsigned short* h16   = agg16 + (size_t)N_PAD*HID;           // N_PAD*HID u16
  float* scaledRel = (float*)(h16 + (size_t)N_PAD*HID);        // REL_VOCAB*HID f32
  float* hrW1      = scaledRel + REL_VOCAB*HID;                // REL_VOCAB*ATTN
  float* alphaS    = hrW1 + REL_VOCAB*ATTN;                    // N_EDGE
  unsigned short* pkWh  = (unsigned short*)(alphaS + N_EDGE);  // 2*4096 u16
  unsigned short* pkWih = pkWh  + 2*4096;                      // 2*12288 u16
  unsigned short* pkWhh = pkWih + 2*12288;                     // 2*12288 u16
  int*   count     = (int*)(pkWhh + 2*12288);                  // 100,004
  int*   startArr  = count + 100004;                           // 100,004
  int*   cursor    = startArr + 100004;                        // 100,004
  int*   bsum      = cursor + 100004;                          // 128
  int*   boff      = bsum + 128;                               // 128
  int*   relS      = boff + 128;                               // N_EDGE
  int*   subS      = relS + N_EDGE;                            // N_EDGE

  // ---- counting sort of edges by obj (packed rel/sub) ----
  k_zero<<<(100004/4+255)/256, 256, 0, stream>>>((float4*)count, 100004/4);
  k_hist<<<(N_EDGE+255)/256, 256, 0, stream>>>(edges, count);
  k_scan1<<<SCAN_NB, 1024, 0, stream>>>(count, startArr, bsum);
  k_scan2<<<1, 64, 0, stream>>>(bsum, boff);
  k_scan3<<<SCAN_NB, 1024, 0, stream>>>(startArr, boff, cursor);
  k_scatter<<<(N_EDGE+255)/256, 256, 0, stream>>>(edges, cursor, relS, subS);

  // ---- per-relation tables + packed bf16 weights ----
  k_pre<<<(REL_VOCAB+255)/256, 256, 0, stream>>>(re, Wr, ww, wb, scaledRel, hrW1);
  k_wt<<<(2*3584+255)/256, 256, 0, stream>>>(Wh, Wih, Whh, pkWh, pkWih, pkWhh);

  const int NB_NODE2 = (N_NODE + 63) / 64;

  // ---- layer 0 ----
  k_agg0<<<(N_NODE*64)/256, 256, 0, stream>>>(startArr, relS, scaledRel, agg16);
  k_node2<0><<<NB_NODE2, 256, 0, stream>>>(agg16, h16,
        pkWh, pkWih, pkWhh, bih, bhh, h16, wf, out, 0);

  // ---- layer 1 ----
  k_alpha<<<(N_EDGE+255)/256, 256, 0, stream>>>(relS, subS, h16, hrW1,
        Ws + ATTN*HID, ww + ATTN, wb + 1, alphaS);
  k_agg1<<<(N_NODE*64)/256, 256, 0, stream>>>(startArr, relS, subS, alphaS,
        h16, re + (size_t)REL_VOCAB*HID, agg16);
  k_node2<1><<<NB_NODE2, 256, 0, stream>>>(agg16, h16,
        pkWh + 4096, pkWih + 12288, pkWhh + 12288, bih + 3*HID, bhh + 3*HID,
        h16, wf, out, 1);
}

// Round 8
// 326.147 us; speedup vs baseline: 18.0628x; 1.1437x over previous
//
#include <hip/hip_runtime.h>

#define N_NODE 100000
#define N_PAD  100064            // padded rows for OOB-safe fragment loads
#define N_EDGE 1000000
#define HID 64
#define ATTN 32
#define REL_VOCAB 2005
#define SCAN_M (N_NODE + 1)
#define SCAN_NB ((SCAN_M + 1023) / 1024)

typedef short  bf16x8 __attribute__((ext_vector_type(8)));
typedef float  f32x4  __attribute__((ext_vector_type(4)));

__device__ __forceinline__ float sigf(float x){ return 1.0f/(1.0f+__expf(-x)); }
__device__ __forceinline__ float bf2f(unsigned short u){
  return __uint_as_float(((unsigned int)u) << 16);
}
__device__ __forceinline__ unsigned short f2bf(float f){  // RNE
  unsigned int x = __float_as_uint(f);
  x += 0x7fffu + ((x >> 16) & 1u);
  return (unsigned short)(x >> 16);
}

__device__ __forceinline__ float dot64(const float4* a, const float4* __restrict__ w){
  float s0=0.f,s1=0.f,s2=0.f,s3=0.f;
  #pragma unroll
  for (int i=0;i<16;i++){
    float4 av=a[i]; float4 wv=w[i];
    s0=fmaf(av.x,wv.x,s0); s1=fmaf(av.y,wv.y,s1);
    s2=fmaf(av.z,wv.z,s2); s3=fmaf(av.w,wv.w,s3);
  }
  return (s0+s1)+(s2+s3);
}

// ---- per-relation precompute: alpha0-scaled rel table (bf16), re1 bf16 copy,
//      and hrW1[r][j] = re1[r] @ Wr1[j] ----
__global__ void __launch_bounds__(256, 2) k_pre(
    const float* __restrict__ re, const float* __restrict__ Wr,
    const float* __restrict__ ww, const float* __restrict__ wb,
    unsigned short* __restrict__ srel16, unsigned short* __restrict__ re16,
    float* __restrict__ hrW1)
{
  int r = blockIdx.x*blockDim.x + threadIdx.x;
  if (r >= REL_VOCAB) return;

  float4 e0[16];
  const float4* re0 = (const float4*)(re + r*HID);
  #pragma unroll
  for (int i=0;i<16;i++) e0[i]=re0[i];

  float acc = wb[0];
  #pragma unroll
  for (int j=0;j<ATTN;j++){
    float d = dot64(e0, (const float4*)(Wr + j*HID));
    d = fmaxf(d, 0.f);
    acc = fmaf(d, ww[j], acc);
  }
  float alpha = sigf(acc);

  #pragma unroll
  for (int i=0;i<16;i++){
    srel16[r*HID + i*4+0] = f2bf(alpha*e0[i].x);
    srel16[r*HID + i*4+1] = f2bf(alpha*e0[i].y);
    srel16[r*HID + i*4+2] = f2bf(alpha*e0[i].z);
    srel16[r*HID + i*4+3] = f2bf(alpha*e0[i].w);
  }

  float4 e1[16];
  const float4* re1p = (const float4*)(re + (REL_VOCAB + r)*HID);
  #pragma unroll
  for (int i=0;i<16;i++) e1[i]=re1p[i];
  #pragma unroll
  for (int i=0;i<16;i++){
    re16[r*HID + i*4+0] = f2bf(e1[i].x);
    re16[r*HID + i*4+1] = f2bf(e1[i].y);
    re16[r*HID + i*4+2] = f2bf(e1[i].z);
    re16[r*HID + i*4+3] = f2bf(e1[i].w);
  }
  #pragma unroll
  for (int j=0;j<ATTN;j++)
    hrW1[r*ATTN+j] = dot64(e1, (const float4*)(Wr + (ATTN+j)*HID));
}

__global__ void k_zero(float4* __restrict__ p, int n4){
  int i = blockIdx.x*blockDim.x + threadIdx.x;
  if (i < n4) p[i] = make_float4(0.f,0.f,0.f,0.f);
}

// ---- weight pack into bf16 MFMA B-fragment order ----
// record layout: 64 lanes x 8 bf16; B[k][col]: col = tile*16 + (l&15),
// k = chunk*32 + (l>>4)*8 + j; source W row-major [outchan][k].
// records: Wh 2li x (4 tiles x 2 chunks); Wih/Whh 2li x (12 x 2); Ws1 (2 x 2).
__global__ void k_wt(const float* __restrict__ Wh, const float* __restrict__ Wih,
                     const float* __restrict__ Whh, const float* __restrict__ Ws,
                     unsigned short* __restrict__ pkWh, unsigned short* __restrict__ pkWih,
                     unsigned short* __restrict__ pkWhh, unsigned short* __restrict__ pkWs)
{
  int tid = blockIdx.x*blockDim.x + threadIdx.x;
  if (tid >= 116*64) return;
  int rec = tid >> 6, l = tid & 63;
  const float* src; unsigned short* dst; int tile, c;
  if (rec < 16){
    int li = rec >> 3, q = rec & 7; tile = q >> 1; c = q & 1;
    src = Wh + li*4096;
    dst = pkWh + (size_t)((li*8 + q)*64 + l)*8;
  } else if (rec < 64){
    int q2 = rec - 16; int li = q2 / 24, q = q2 % 24; tile = q >> 1; c = q & 1;
    src = Wih + li*12288;
    dst = pkWih + (size_t)((li*24 + q)*64 + l)*8;
  } else if (rec < 112){
    int q2 = rec - 64; int li = q2 / 24, q = q2 % 24; tile = q >> 1; c = q & 1;
    src = Whh + li*12288;
    dst = pkWhh + (size_t)((li*24 + q)*64 + l)*8;
  } else {
    int q = rec - 112; tile = q >> 1; c = q & 1;
    src = Ws + ATTN*HID;                       // layer-1 Ws only
    dst = pkWs + (size_t)(q*64 + l)*8;
  }
  int row = tile*16 + (l&15);
  int k0  = c*32 + (l>>4)*8;
  #pragma unroll
  for (int j=0;j<8;j++) dst[j] = f2bf(src[row*64 + k0 + j]);
}

// ---- counting sort of edges by obj ----
__global__ void k_hist(const int* __restrict__ edges, int* __restrict__ count){
  int e = blockIdx.x*blockDim.x + threadIdx.x;
  if (e >= N_EDGE) return;
  atomicAdd(&count[edges[e*6+5]], 1);
}

__global__ void k_scan1(const int* __restrict__ count, int* __restrict__ start,
                        int* __restrict__ bsum)
{
  __shared__ int s[1024];
  int tid = threadIdx.x;
  int i = blockIdx.x*1024 + tid;
  int v = (i < SCAN_M) ? count[i] : 0;
  s[tid] = v; __syncthreads();
  #pragma unroll
  for (int off=1; off<1024; off<<=1){
    int t = (tid>=off) ? s[tid-off] : 0;
    __syncthreads();
    s[tid] += t;
    __syncthreads();
  }
  if (i < SCAN_M) start[i] = s[tid] - v;
  if (tid == 1023) bsum[blockIdx.x] = s[1023];
}

__global__ void k_scan2(const int* __restrict__ bsum, int* __restrict__ boff){
  if (threadIdx.x == 0){
    int run = 0;
    for (int b=0;b<SCAN_NB;b++){ boff[b]=run; run+=bsum[b]; }
  }
}

__global__ void k_scan3(int* __restrict__ start, const int* __restrict__ boff,
                        int* __restrict__ cursor)
{
  int i = blockIdx.x*1024 + threadIdx.x;
  if (i >= SCAN_M) return;
  int v = start[i] + boff[blockIdx.x];
  start[i] = v;
  if (i < N_NODE) cursor[i] = v;
}

__global__ void k_scatter(const int* __restrict__ edges, int* __restrict__ cursor,
                          int* __restrict__ relS, int* __restrict__ subS)
{
  int e = blockIdx.x*blockDim.x + threadIdx.x;
  if (e >= N_EDGE) return;
  int obj = edges[e*6+5];
  int rel = edges[e*6+2];
  int sub = edges[e*6+4];
  int pos = atomicAdd(&cursor[obj], 1);
  relS[pos] = rel;
  subS[pos] = sub;
}

// ---- layer-0 aggregation: wave per node (bf16 table) -> bf16 agg ----
__global__ void k_agg0(const int* __restrict__ startArr, const int* __restrict__ relS,
                       const unsigned short* __restrict__ srel16,
                       unsigned short* __restrict__ agg16)
{
  int t = blockIdx.x*blockDim.x + threadIdx.x;
  int n = __builtin_amdgcn_readfirstlane(t >> 6);
  int k = t & 63;
  if (n >= N_NODE) return;
  int b = startArr[n], e_ = startArr[n+1];
  float acc = 0.f;
  int i = b;
  for (; i+3 < e_; i += 4){
    int r0=relS[i], r1=relS[i+1], r2=relS[i+2], r3=relS[i+3];
    float v0=bf2f(srel16[r0*HID+k]), v1=bf2f(srel16[r1*HID+k]);
    float v2=bf2f(srel16[r2*HID+k]), v3=bf2f(srel16[r3*HID+k]);
    acc += v0; acc += v1; acc += v2; acc += v3;
  }
  for (; i < e_; ++i) acc += bf2f(srel16[relS[i]*HID + k]);
  agg16[(size_t)n*HID + k] = f2bf(acc);
}

// ---- layer-1 per-edge alpha via MFMA: wave = 16 edges ----
// A-frag: edge row = l&15, gathered from h16[sub]; B = packed Ws1;
// epilogue adds hrW1[rel], relu, dot ww1 (shfl-xor over the 16 col-lanes),
// sigmoid -> alphaS (float4 store per lg group).
__global__ void __launch_bounds__(256, 4) k_alphaM(
    const int* __restrict__ relS, const int* __restrict__ subS,
    const unsigned short* __restrict__ h16,
    const float* __restrict__ hrW1, const unsigned short* __restrict__ pkWs,
    const float* __restrict__ ww1, const float* __restrict__ wb1,
    float* __restrict__ alphaS)
{
  const int t = threadIdx.x;
  const int w = t >> 6, l = t & 63;
  const int lr = l & 15, lg = l >> 4;
  const int i0 = (blockIdx.x*4 + w) * 16;     // exact: N_EDGE = 64 * gridDim

  int subA = subS[i0 + lr];
  bf16x8 a0 = *(const bf16x8*)(h16 + (size_t)subA*HID + lg*8);
  bf16x8 a1 = *(const bf16x8*)(h16 + (size_t)subA*HID + 32 + lg*8);

  bf16x8 b00 = *(const bf16x8*)(pkWs + (size_t)(0*64 + l)*8);  // ct0,c0
  bf16x8 b01 = *(const bf16x8*)(pkWs + (size_t)(1*64 + l)*8);  // ct0,c1
  bf16x8 b10 = *(const bf16x8*)(pkWs + (size_t)(2*64 + l)*8);  // ct1,c0
  bf16x8 b11 = *(const bf16x8*)(pkWs + (size_t)(3*64 + l)*8);  // ct1,c1

  f32x4 acc0 = {0.f,0.f,0.f,0.f}, acc1 = {0.f,0.f,0.f,0.f};
  acc0 = __builtin_amdgcn_mfma_f32_16x16x32_bf16(a0, b00, acc0, 0,0,0);
  acc0 = __builtin_amdgcn_mfma_f32_16x16x32_bf16(a1, b01, acc0, 0,0,0);
  acc1 = __builtin_amdgcn_mfma_f32_16x16x32_bf16(a0, b10, acc1, 0,0,0);
  acc1 = __builtin_amdgcn_mfma_f32_16x16x32_bf16(a1, b11, acc1, 0,0,0);

  float wlo = ww1[lr], whi = ww1[16 + lr];
  float bias = wb1[0];
  float s[4];
  #pragma unroll
  for (int r=0;r<4;r++){
    int e = i0 + lg*4 + r;
    int rel = relS[e];
    float v0 = fmaxf(acc0[r] + hrW1[rel*ATTN + lr],      0.f);
    float v1 = fmaxf(acc1[r] + hrW1[rel*ATTN + 16 + lr], 0.f);
    float p = fmaf(v0, wlo, v1*whi);
    p += __shfl_xor(p, 1);
    p += __shfl_xor(p, 2);
    p += __shfl_xor(p, 4);
    p += __shfl_xor(p, 8);
    s[r] = sigf(p + bias);
  }
  if (lr == 0)
    *(float4*)(alphaS + i0 + lg*4) = make_float4(s[0], s[1], s[2], s[3]);
}

// ---- layer-1 aggregation: wave per node; bf16 h + bf16 re1 -> bf16 agg ----
__global__ void k_agg1(const int* __restrict__ startArr, const int* __restrict__ relS,
                       const int* __restrict__ subS, const float* __restrict__ alphaS,
                       const unsigned short* __restrict__ h16,
                       const unsigned short* __restrict__ re16,
                       unsigned short* __restrict__ agg16)
{
  int t = blockIdx.x*blockDim.x + threadIdx.x;
  int n = __builtin_amdgcn_readfirstlane(t >> 6);
  int k = t & 63;
  if (n >= N_NODE) return;
  int b = startArr[n], e_ = startArr[n+1];
  float acc = 0.f;
  int i = b;
  for (; i+1 < e_; i += 2){
    int r0 = relS[i],   s0 = subS[i];
    int r1 = relS[i+1], s1 = subS[i+1];
    float al0 = alphaS[i], al1 = alphaS[i+1];
    float h0 = bf2f(h16[(size_t)s0*HID + k]);
    float h1 = bf2f(h16[(size_t)s1*HID + k]);
    float v0 = bf2f(re16[r0*HID + k]);
    float v1 = bf2f(re16[r1*HID + k]);
    acc = fmaf(al0, h0 + v0, acc);
    acc = fmaf(al1, h1 + v1, acc);
  }
  if (i < e_){
    int r0 = relS[i], s0 = subS[i];
    acc = fmaf(alphaS[i], bf2f(h16[(size_t)s0*HID + k]) + bf2f(re16[r0*HID + k]), acc);
  }
  agg16[(size_t)n*HID + k] = f2bf(acc);
}

// ---- MFMA node phase: 64 nodes/block, wave w owns nodes w*16..w*16+15 ----
template<int HAS_H0>
__global__ void __launch_bounds__(256, 2) k_node2(
    const unsigned short* __restrict__ agg16,
    const unsigned short* __restrict__ h16,
    const unsigned short* __restrict__ pkWh,
    const unsigned short* __restrict__ pkWih,
    const unsigned short* __restrict__ pkWhh,
    const float* __restrict__ bih, const float* __restrict__ bhh,
    unsigned short* __restrict__ h16_out,
    const float* __restrict__ wf, float* __restrict__ score, int mode)
{
  __shared__ unsigned short xlds[4096];   // 4 waves x [16 rows][64 cols] bf16, swizzled

  const int t  = threadIdx.x;
  const int w  = t >> 6, l = t & 63;
  const int lr = l & 15;                  // fragment row/col
  const int lg = l >> 4;                  // k-group
  const int n0 = blockIdx.x * 64;
  const int rowA = n0 + w*16 + lr;

  bf16x8 aA0 = *(const bf16x8*)(agg16 + (size_t)rowA*HID + lg*8);
  bf16x8 aA1 = *(const bf16x8*)(agg16 + (size_t)rowA*HID + 32 + lg*8);
  bf16x8 hA0, hA1;
  if (HAS_H0){
    hA0 = *(const bf16x8*)(h16 + (size_t)rowA*HID + lg*8);
    hA1 = *(const bf16x8*)(h16 + (size_t)rowA*HID + 32 + lg*8);
  }

  float bir[4],biz[4],bin[4],bhr[4],bhz[4],bhn[4],wfv[4];
  #pragma unroll
  for (int nt=0;nt<4;nt++){
    int ch = nt*16 + lr;
    bir[nt]=bih[ch]; biz[nt]=bih[64+ch]; bin[nt]=bih[128+ch];
    bhr[nt]=bhh[ch]; bhz[nt]=bhh[64+ch]; bhn[nt]=bhh[128+ch];
    wfv[nt]=wf[ch];
  }

  // ---- X = relu(agg @ Wh^T) ----
  #pragma unroll
  for (int nt=0;nt<4;nt++){
    f32x4 acc = {0.f,0.f,0.f,0.f};
    bf16x8 b0 = *(const bf16x8*)(pkWh + (size_t)((nt*2+0)*64 + l)*8);
    bf16x8 b1 = *(const bf16x8*)(pkWh + (size_t)((nt*2+1)*64 + l)*8);
    acc = __builtin_amdgcn_mfma_f32_16x16x32_bf16(aA0, b0, acc, 0,0,0);
    acc = __builtin_amdgcn_mfma_f32_16x16x32_bf16(aA1, b1, acc, 0,0,0);
    #pragma unroll
    for (int r=0;r<4;r++){
      int m = lg*4 + r, col = nt*16 + lr;
      xlds[w*1024 + m*64 + (col ^ ((m&7)<<3))] = f2bf(fmaxf(acc[r], 0.f));
    }
  }
  __syncthreads();

  const int xbase = w*1024 + lr*64;
  const int sw = (lr&7)<<3;
  bf16x8 xA0 = *(const bf16x8*)&xlds[xbase + ((lg*8)      ^ sw)];
  bf16x8 xA1 = *(const bf16x8*)&xlds[xbase + ((32 + lg*8) ^ sw)];

  // ---- gate passes ----
  float rv[16], zv[16], hv[16];
  #pragma unroll
  for (int g=0; g<2; ++g){               // g=0: r-gate, g=1: z-gate
    #pragma unroll
    for (int nt=0;nt<4;nt++){
      int gt = g*4 + nt;
      f32x4 ai = {0.f,0.f,0.f,0.f};
      bf16x8 bi0 = *(const bf16x8*)(pkWih + (size_t)((gt*2+0)*64 + l)*8);
      bf16x8 bi1 = *(const bf16x8*)(pkWih + (size_t)((gt*2+1)*64 + l)*8);
      ai = __builtin_amdgcn_mfma_f32_16x16x32_bf16(xA0, bi0, ai, 0,0,0);
      ai = __builtin_amdgcn_mfma_f32_16x16x32_bf16(xA1, bi1, ai, 0,0,0);
      f32x4 ah = {0.f,0.f,0.f,0.f};
      if (HAS_H0){
        bf16x8 bh0 = *(const bf16x8*)(pkWhh + (size_t)((gt*2+0)*64 + l)*8);
        bf16x8 bh1 = *(const bf16x8*)(pkWhh + (size_t)((gt*2+1)*64 + l)*8);
        ah = __builtin_amdgcn_mfma_f32_16x16x32_bf16(hA0, bh0, ah, 0,0,0);
        ah = __builtin_amdgcn_mfma_f32_16x16x32_bf16(hA1, bh1, ah, 0,0,0);
      }
      #pragma unroll
      for (int r=0;r<4;r++){
        float bi_ = (g==0) ? bir[nt] : biz[nt];
        float bh_ = (g==0) ? bhr[nt] : bhz[nt];
        float v = sigf(ai[r] + bi_ + ah[r] + bh_);
        if (g==0) rv[nt*4+r] = v; else zv[nt*4+r] = v;
      }
    }
  }
  #pragma unroll
  for (int nt=0;nt<4;nt++){              // n-gate + GRU blend
    int gt = 8 + nt;
    f32x4 ai = {0.f,0.f,0.f,0.f};
    bf16x8 bi0 = *(const bf16x8*)(pkWih + (size_t)((gt*2+0)*64 + l)*8);
    bf16x8 bi1 = *(const bf16x8*)(pkWih + (size_t)((gt*2+1)*64 + l)*8);
    ai = __builtin_amdgcn_mfma_f32_16x16x32_bf16(xA0, bi0, ai, 0,0,0);
    ai = __builtin_amdgcn_mfma_f32_16x16x32_bf16(xA1, bi1, ai, 0,0,0);
    f32x4 ah = {0.f,0.f,0.f,0.f};
    if (HAS_H0){
      bf16x8 bh0 = *(const bf16x8*)(pkWhh + (size_t)((gt*2+0)*64 + l)*8);
      bf16x8 bh1 = *(const bf16x8*)(pkWhh + (size_t)((gt*2+1)*64 + l)*8);
      ah = __builtin_amdgcn_mfma_f32_16x16x32_bf16(hA0, bh0, ah, 0,0,0);
      ah = __builtin_amdgcn_mfma_f32_16x16x32_bf16(hA1, bh1, ah, 0,0,0);
    }
    #pragma unroll
    for (int r=0;r<4;r++){
      float gin = ai[r] + bin[nt];
      float ghn = ah[r] + bhn[nt];
      float rr  = rv[nt*4+r];
      float nn  = tanhf(fmaf(rr, ghn, gin));
      float z   = zv[nt*4+r];
      float h0v = 0.f;
      if (HAS_H0)
        h0v = bf2f(h16[(size_t)(n0 + w*16 + lg*4 + r)*HID + nt*16 + lr]);
      hv[nt*4+r] = (1.f - z)*nn + z*h0v;
    }
  }

  if (mode == 0){
    __syncthreads();
    #pragma unroll
    for (int nt=0;nt<4;nt++)
      #pragma unroll
      for (int r=0;r<4;r++){
        int m = lg*4 + r, col = nt*16 + lr;
        xlds[w*1024 + m*64 + (col ^ ((m&7)<<3))] = f2bf(hv[nt*4+r]);
      }
    __syncthreads();
    int rr2 = l >> 2, cc = l & 3;
    int n = n0 + w*16 + rr2;
    if (n < N_NODE){
      int base = w*1024 + rr2*64, s2 = (rr2&7)<<3;
      bf16x8 v0 = *(const bf16x8*)&xlds[base + ((cc*16)     ^ s2)];
      bf16x8 v1 = *(const bf16x8*)&xlds[base + ((cc*16 + 8) ^ s2)];
      *(bf16x8*)(h16_out + (size_t)n*HID + cc*16)     = v0;
      *(bf16x8*)(h16_out + (size_t)n*HID + cc*16 + 8) = v1;
    }
  } else {
    #pragma unroll
    for (int r=0;r<4;r++){
      float p = 0.f;
      #pragma unroll
      for (int nt=0;nt<4;nt++) p = fmaf(hv[nt*4+r], wfv[nt], p);
      p += __shfl_xor(p, 1);
      p += __shfl_xor(p, 2);
      p += __shfl_xor(p, 4);
      p += __shfl_xor(p, 8);
      if (lr == 0){
        int n = n0 + w*16 + lg*4 + r;
        if (n < N_NODE) score[n] = p;
      }
    }
  }
}

extern "C" void kernel_launch(void* const* d_in, const int* in_sizes, int n_in,
                              void* d_out, int out_size, void* d_ws, size_t ws_size,
                              hipStream_t stream)
{
  const int*   edges = (const int*)  d_in[0];
  const float* re    = (const float*)d_in[1];
  const float* Ws    = (const float*)d_in[2];
  const float* Wr    = (const float*)d_in[3];
  const float* ww    = (const float*)d_in[4];
  const float* wb    = (const float*)d_in[5];
  const float* Wh    = (const float*)d_in[6];
  const float* Wih   = (const float*)d_in[7];
  const float* Whh   = (const float*)d_in[8];
  const float* bih   = (const float*)d_in[9];
  const float* bhh   = (const float*)d_in[10];
  const float* wf    = (const float*)d_in[11];
  float* out = (float*)d_out;

  // workspace layout (u16 block first, then f32, then int)
  unsigned short* agg16  = (unsigned short*)d_ws;              // N_PAD*HID
  unsigned short* h16    = agg16 + (size_t)N_PAD*HID;          // N_PAD*HID
  unsigned short* srel16 = h16 + (size_t)N_PAD*HID;            // REL_VOCAB*HID
  unsigned short* re16   = srel16 + REL_VOCAB*HID;             // REL_VOCAB*HID
  unsigned short* pkWh   = re16 + REL_VOCAB*HID;               // 2*4096
  unsigned short* pkWih  = pkWh  + 2*4096;                     // 2*12288
  unsigned short* pkWhh  = pkWih + 2*12288;                    // 2*12288
  unsigned short* pkWs   = pkWhh + 2*12288;                    // 4*64*8 = 2048
  float* hrW1      = (float*)(pkWs + 2048);                    // REL_VOCAB*ATTN
  float* alphaS    = hrW1 + REL_VOCAB*ATTN;                    // N_EDGE
  int*   count     = (int*)(alphaS + N_EDGE);                  // 100,004
  int*   startArr  = count + 100004;                           // 100,004
  int*   cursor    = startArr + 100004;                        // 100,004
  int*   bsum      = cursor + 100004;                          // 128
  int*   boff      = bsum + 128;                               // 128
  int*   relS      = boff + 128;                               // N_EDGE
  int*   subS      = relS + N_EDGE;                            // N_EDGE

  // ---- counting sort of edges by obj (packed rel/sub) ----
  k_zero<<<(100004/4+255)/256, 256, 0, stream>>>((float4*)count, 100004/4);
  k_hist<<<(N_EDGE+255)/256, 256, 0, stream>>>(edges, count);
  k_scan1<<<SCAN_NB, 1024, 0, stream>>>(count, startArr, bsum);
  k_scan2<<<1, 64, 0, stream>>>(bsum, boff);
  k_scan3<<<SCAN_NB, 1024, 0, stream>>>(startArr, boff, cursor);
  k_scatter<<<(N_EDGE+255)/256, 256, 0, stream>>>(edges, cursor, relS, subS);

  // ---- per-relation tables + packed bf16 weights ----
  k_pre<<<(REL_VOCAB+255)/256, 256, 0, stream>>>(re, Wr, ww, wb, srel16, re16, hrW1);
  k_wt<<<(116*64+255)/256, 256, 0, stream>>>(Wh, Wih, Whh, Ws, pkWh, pkWih, pkWhh, pkWs);

  const int NB_NODE2 = (N_NODE + 63) / 64;

  // ---- layer 0 ----
  k_agg0<<<(N_NODE*64)/256, 256, 0, stream>>>(startArr, relS, srel16, agg16);
  k_node2<0><<<NB_NODE2, 256, 0, stream>>>(agg16, h16,
        pkWh, pkWih, pkWhh, bih, bhh, h16, wf, out, 0);

  // ---- layer 1 ----
  k_alphaM<<<N_EDGE/64, 256, 0, stream>>>(relS, subS, h16, hrW1, pkWs,
        ww + ATTN, wb + 1, alphaS);
  k_agg1<<<(N_NODE*64)/256, 256, 0, stream>>>(startArr, relS, subS, alphaS,
        h16, re16, agg16);
  k_node2<1><<<NB_NODE2, 256, 0, stream>>>(agg16, h16,
        pkWh + 4096, pkWih + 12288, pkWhh + 12288, bih + 3*HID, bhh + 3*HID,
        h16, wf, out, 1);
}

// Round 9
// 281.895 us; speedup vs baseline: 20.8983x; 1.1570x over previous
//
#include <hip/hip_runtime.h>

#define N_NODE 100000
#define N_PAD  100064            // padded rows for OOB-safe fragment loads
#define N_EDGE 1000000
#define HID 64
#define ATTN 32
#define REL_VOCAB 2005
#define SCAN_M (N_NODE + 1)
#define SCAN_NB ((SCAN_M + 1023) / 1024)

typedef short  bf16x8 __attribute__((ext_vector_type(8)));
typedef float  f32x4  __attribute__((ext_vector_type(4)));

__device__ __forceinline__ float sigf(float x){ return 1.0f/(1.0f+__expf(-x)); }
__device__ __forceinline__ float bf2f(unsigned short u){
  return __uint_as_float(((unsigned int)u) << 16);
}
__device__ __forceinline__ unsigned short f2bf(float f){  // RNE
  unsigned int x = __float_as_uint(f);
  x += 0x7fffu + ((x >> 16) & 1u);
  return (unsigned short)(x >> 16);
}

__device__ __forceinline__ float dot64(const float4* a, const float4* __restrict__ w){
  float s0=0.f,s1=0.f,s2=0.f,s3=0.f;
  #pragma unroll
  for (int i=0;i<16;i++){
    float4 av=a[i]; float4 wv=w[i];
    s0=fmaf(av.x,wv.x,s0); s1=fmaf(av.y,wv.y,s1);
    s2=fmaf(av.z,wv.z,s2); s3=fmaf(av.w,wv.w,s3);
  }
  return (s0+s1)+(s2+s3);
}

// ---- per-relation precompute, wave-parallel: one wave per relation ----
// lanes 0..31: layer-0 j-dot (relu, *ww[j]) -> full-wave shfl reduce -> alpha
// lanes 32..63: layer-1 j-dot -> hrW1[r][j]
// then lane l writes element l of srel16 (alpha-scaled) and re16.
__global__ void __launch_bounds__(256, 4) k_pre(
    const float* __restrict__ re, const float* __restrict__ Wr,
    const float* __restrict__ ww, const float* __restrict__ wb,
    unsigned short* __restrict__ srel16, unsigned short* __restrict__ re16,
    float* __restrict__ hrW1)
{
  int w = (blockIdx.x*blockDim.x + threadIdx.x) >> 6;
  int l = threadIdx.x & 63;
  if (w >= REL_VOCAB) return;
  const int r = w;
  const int j = l & 31;
  const bool hi = (l >= 32);

  // each lane loads the full embed row it needs (L1/L2-resident, 256B)
  float4 ev[16];
  const float4* ep = (const float4*)(re + (size_t)(hi ? REL_VOCAB + r : r)*HID);
  #pragma unroll
  for (int i=0;i<16;i++) ev[i]=ep[i];

  const float4* wrow = (const float4*)(Wr + (size_t)(hi ? ATTN + j : j)*HID);
  float d = dot64(ev, wrow);

  if (hi) hrW1[r*ATTN + j] = d;

  float p = hi ? 0.f : fmaxf(d, 0.f) * ww[j];
  p += __shfl_xor(p, 1);
  p += __shfl_xor(p, 2);
  p += __shfl_xor(p, 4);
  p += __shfl_xor(p, 8);
  p += __shfl_xor(p, 16);
  p += __shfl_xor(p, 32);
  float alpha = sigf(p + wb[0]);

  float e0l = re[(size_t)r*HID + l];
  float e1l = re[(size_t)(REL_VOCAB + r)*HID + l];
  srel16[r*HID + l] = f2bf(alpha * e0l);
  re16[r*HID + l]   = f2bf(e1l);
}

__global__ void k_zero(float4* __restrict__ p, int n4){
  int i = blockIdx.x*blockDim.x + threadIdx.x;
  if (i < n4) p[i] = make_float4(0.f,0.f,0.f,0.f);
}

// ---- weight pack into bf16 MFMA B-fragment order ----
__global__ void k_wt(const float* __restrict__ Wh, const float* __restrict__ Wih,
                     const float* __restrict__ Whh, const float* __restrict__ Ws,
                     unsigned short* __restrict__ pkWh, unsigned short* __restrict__ pkWih,
                     unsigned short* __restrict__ pkWhh, unsigned short* __restrict__ pkWs)
{
  int tid = blockIdx.x*blockDim.x + threadIdx.x;
  if (tid >= 116*64) return;
  int rec = tid >> 6, l = tid & 63;
  const float* src; unsigned short* dst; int tile, c;
  if (rec < 16){
    int li = rec >> 3, q = rec & 7; tile = q >> 1; c = q & 1;
    src = Wh + li*4096;
    dst = pkWh + (size_t)((li*8 + q)*64 + l)*8;
  } else if (rec < 64){
    int q2 = rec - 16; int li = q2 / 24, q = q2 % 24; tile = q >> 1; c = q & 1;
    src = Wih + li*12288;
    dst = pkWih + (size_t)((li*24 + q)*64 + l)*8;
  } else if (rec < 112){
    int q2 = rec - 64; int li = q2 / 24, q = q2 % 24; tile = q >> 1; c = q & 1;
    src = Whh + li*12288;
    dst = pkWhh + (size_t)((li*24 + q)*64 + l)*8;
  } else {
    int q = rec - 112; tile = q >> 1; c = q & 1;
    src = Ws + ATTN*HID;                       // layer-1 Ws only
    dst = pkWs + (size_t)(q*64 + l)*8;
  }
  int row = tile*16 + (l&15);
  int k0  = c*32 + (l>>4)*8;
  #pragma unroll
  for (int j=0;j<8;j++) dst[j] = f2bf(src[row*64 + k0 + j]);
}

// ---- counting sort of edges by obj ----
__global__ void k_hist(const int* __restrict__ edges, int* __restrict__ count){
  int e = blockIdx.x*blockDim.x + threadIdx.x;
  if (e >= N_EDGE) return;
  atomicAdd(&count[edges[e*6+5]], 1);
}

__global__ void k_scan1(const int* __restrict__ count, int* __restrict__ start,
                        int* __restrict__ bsum)
{
  __shared__ int s[1024];
  int tid = threadIdx.x;
  int i = blockIdx.x*1024 + tid;
  int v = (i < SCAN_M) ? count[i] : 0;
  s[tid] = v; __syncthreads();
  #pragma unroll
  for (int off=1; off<1024; off<<=1){
    int t = (tid>=off) ? s[tid-off] : 0;
    __syncthreads();
    s[tid] += t;
    __syncthreads();
  }
  if (i < SCAN_M) start[i] = s[tid] - v;
  if (tid == 1023) bsum[blockIdx.x] = s[1023];
}

__global__ void k_scan2(const int* __restrict__ bsum, int* __restrict__ boff){
  if (threadIdx.x == 0){
    int run = 0;
    for (int b=0;b<SCAN_NB;b++){ boff[b]=run; run+=bsum[b]; }
  }
}

__global__ void k_scan3(int* __restrict__ start, const int* __restrict__ boff,
                        int* __restrict__ cursor)
{
  int i = blockIdx.x*1024 + threadIdx.x;
  if (i >= SCAN_M) return;
  int v = start[i] + boff[blockIdx.x];
  start[i] = v;
  if (i < N_NODE) cursor[i] = v;
}

// scatter: single packed 8B store per edge (rel, sub)
__global__ void k_scatter(const int* __restrict__ edges, int* __restrict__ cursor,
                          int2* __restrict__ pairS)
{
  int e = blockIdx.x*blockDim.x + threadIdx.x;
  if (e >= N_EDGE) return;
  int obj = edges[e*6+5];
  int rel = edges[e*6+2];
  int sub = edges[e*6+4];
  int pos = atomicAdd(&cursor[obj], 1);
  pairS[pos] = make_int2(rel, sub);
}

// ---- layer-0 aggregation: wave per node (bf16 table) -> bf16 agg ----
__global__ void k_agg0(const int* __restrict__ startArr, const int2* __restrict__ pairS,
                       const unsigned short* __restrict__ srel16,
                       unsigned short* __restrict__ agg16)
{
  int t = blockIdx.x*blockDim.x + threadIdx.x;
  int n = __builtin_amdgcn_readfirstlane(t >> 6);
  int k = t & 63;
  if (n >= N_NODE) return;
  int b = startArr[n], e_ = startArr[n+1];
  float acc = 0.f;
  int i = b;
  for (; i+3 < e_; i += 4){
    int r0=pairS[i].x, r1=pairS[i+1].x, r2=pairS[i+2].x, r3=pairS[i+3].x;
    float v0=bf2f(srel16[r0*HID+k]), v1=bf2f(srel16[r1*HID+k]);
    float v2=bf2f(srel16[r2*HID+k]), v3=bf2f(srel16[r3*HID+k]);
    acc += v0; acc += v1; acc += v2; acc += v3;
  }
  for (; i < e_; ++i) acc += bf2f(srel16[pairS[i].x*HID + k]);
  agg16[(size_t)n*HID + k] = f2bf(acc);
}

// ---- layer-1 per-edge alpha via MFMA: wave = 16 edges ----
__global__ void __launch_bounds__(256, 4) k_alphaM(
    const int2* __restrict__ pairS,
    const unsigned short* __restrict__ h16,
    const float* __restrict__ hrW1, const unsigned short* __restrict__ pkWs,
    const float* __restrict__ ww1, const float* __restrict__ wb1,
    float* __restrict__ alphaS)
{
  const int t = threadIdx.x;
  const int w = t >> 6, l = t & 63;
  const int lr = l & 15, lg = l >> 4;
  const int i0 = (blockIdx.x*4 + w) * 16;     // exact: N_EDGE = 64 * gridDim

  int subA = pairS[i0 + lr].y;
  bf16x8 a0 = *(const bf16x8*)(h16 + (size_t)subA*HID + lg*8);
  bf16x8 a1 = *(const bf16x8*)(h16 + (size_t)subA*HID + 32 + lg*8);

  bf16x8 b00 = *(const bf16x8*)(pkWs + (size_t)(0*64 + l)*8);
  bf16x8 b01 = *(const bf16x8*)(pkWs + (size_t)(1*64 + l)*8);
  bf16x8 b10 = *(const bf16x8*)(pkWs + (size_t)(2*64 + l)*8);
  bf16x8 b11 = *(const bf16x8*)(pkWs + (size_t)(3*64 + l)*8);

  f32x4 acc0 = {0.f,0.f,0.f,0.f}, acc1 = {0.f,0.f,0.f,0.f};
  acc0 = __builtin_amdgcn_mfma_f32_16x16x32_bf16(a0, b00, acc0, 0,0,0);
  acc0 = __builtin_amdgcn_mfma_f32_16x16x32_bf16(a1, b01, acc0, 0,0,0);
  acc1 = __builtin_amdgcn_mfma_f32_16x16x32_bf16(a0, b10, acc1, 0,0,0);
  acc1 = __builtin_amdgcn_mfma_f32_16x16x32_bf16(a1, b11, acc1, 0,0,0);

  float wlo = ww1[lr], whi = ww1[16 + lr];
  float bias = wb1[0];
  float s[4];
  #pragma unroll
  for (int r=0;r<4;r++){
    int e = i0 + lg*4 + r;
    int rel = pairS[e].x;
    float v0 = fmaxf(acc0[r] + hrW1[rel*ATTN + lr],      0.f);
    float v1 = fmaxf(acc1[r] + hrW1[rel*ATTN + 16 + lr], 0.f);
    float p = fmaf(v0, wlo, v1*whi);
    p += __shfl_xor(p, 1);
    p += __shfl_xor(p, 2);
    p += __shfl_xor(p, 4);
    p += __shfl_xor(p, 8);
    s[r] = sigf(p + bias);
  }
  if (lr == 0)
    *(float4*)(alphaS + i0 + lg*4) = make_float4(s[0], s[1], s[2], s[3]);
}

// ---- layer-1 aggregation: wave per node; bf16 h + bf16 re1 -> bf16 agg ----
__global__ void k_agg1(const int* __restrict__ startArr, const int2* __restrict__ pairS,
                       const float* __restrict__ alphaS,
                       const unsigned short* __restrict__ h16,
                       const unsigned short* __restrict__ re16,
                       unsigned short* __restrict__ agg16)
{
  int t = blockIdx.x*blockDim.x + threadIdx.x;
  int n = __builtin_amdgcn_readfirstlane(t >> 6);
  int k = t & 63;
  if (n >= N_NODE) return;
  int b = startArr[n], e_ = startArr[n+1];
  float acc = 0.f;
  int i = b;
  for (; i+1 < e_; i += 2){
    int2 p0 = pairS[i], p1 = pairS[i+1];
    float al0 = alphaS[i], al1 = alphaS[i+1];
    float h0 = bf2f(h16[(size_t)p0.y*HID + k]);
    float h1 = bf2f(h16[(size_t)p1.y*HID + k]);
    float v0 = bf2f(re16[p0.x*HID + k]);
    float v1 = bf2f(re16[p1.x*HID + k]);
    acc = fmaf(al0, h0 + v0, acc);
    acc = fmaf(al1, h1 + v1, acc);
  }
  if (i < e_){
    int2 p0 = pairS[i];
    acc = fmaf(alphaS[i], bf2f(h16[(size_t)p0.y*HID + k]) + bf2f(re16[p0.x*HID + k]), acc);
  }
  agg16[(size_t)n*HID + k] = f2bf(acc);
}

// ---- MFMA node phase: 64 nodes/block, wave w owns nodes w*16..w*16+15 ----
template<int HAS_H0>
__global__ void __launch_bounds__(256, 2) k_node2(
    const unsigned short* __restrict__ agg16,
    const unsigned short* __restrict__ h16,
    const unsigned short* __restrict__ pkWh,
    const unsigned short* __restrict__ pkWih,
    const unsigned short* __restrict__ pkWhh,
    const float* __restrict__ bih, const float* __restrict__ bhh,
    unsigned short* __restrict__ h16_out,
    const float* __restrict__ wf, float* __restrict__ score, int mode)
{
  __shared__ unsigned short xlds[4096];   // 4 waves x [16 rows][64 cols] bf16, swizzled

  const int t  = threadIdx.x;
  const int w  = t >> 6, l = t & 63;
  const int lr = l & 15;                  // fragment row/col
  const int lg = l >> 4;                  // k-group
  const int n0 = blockIdx.x * 64;
  const int rowA = n0 + w*16 + lr;

  bf16x8 aA0 = *(const bf16x8*)(agg16 + (size_t)rowA*HID + lg*8);
  bf16x8 aA1 = *(const bf16x8*)(agg16 + (size_t)rowA*HID + 32 + lg*8);
  bf16x8 hA0, hA1;
  if (HAS_H0){
    hA0 = *(const bf16x8*)(h16 + (size_t)rowA*HID + lg*8);
    hA1 = *(const bf16x8*)(h16 + (size_t)rowA*HID + 32 + lg*8);
  }

  float bir[4],biz[4],bin[4],bhr[4],bhz[4],bhn[4],wfv[4];
  #pragma unroll
  for (int nt=0;nt<4;nt++){
    int ch = nt*16 + lr;
    bir[nt]=bih[ch]; biz[nt]=bih[64+ch]; bin[nt]=bih[128+ch];
    bhr[nt]=bhh[ch]; bhz[nt]=bhh[64+ch]; bhn[nt]=bhh[128+ch];
    wfv[nt]=wf[ch];
  }

  // ---- X = relu(agg @ Wh^T) ----
  #pragma unroll
  for (int nt=0;nt<4;nt++){
    f32x4 acc = {0.f,0.f,0.f,0.f};
    bf16x8 b0 = *(const bf16x8*)(pkWh + (size_t)((nt*2+0)*64 + l)*8);
    bf16x8 b1 = *(const bf16x8*)(pkWh + (size_t)((nt*2+1)*64 + l)*8);
    acc = __builtin_amdgcn_mfma_f32_16x16x32_bf16(aA0, b0, acc, 0,0,0);
    acc = __builtin_amdgcn_mfma_f32_16x16x32_bf16(aA1, b1, acc, 0,0,0);
    #pragma unroll
    for (int r=0;r<4;r++){
      int m = lg*4 + r, col = nt*16 + lr;
      xlds[w*1024 + m*64 + (col ^ ((m&7)<<3))] = f2bf(fmaxf(acc[r], 0.f));
    }
  }
  __syncthreads();

  const int xbase = w*1024 + lr*64;
  const int sw = (lr&7)<<3;
  bf16x8 xA0 = *(const bf16x8*)&xlds[xbase + ((lg*8)      ^ sw)];
  bf16x8 xA1 = *(const bf16x8*)&xlds[xbase + ((32 + lg*8) ^ sw)];

  // ---- gate passes ----
  float rv[16], zv[16], hv[16];
  #pragma unroll
  for (int g=0; g<2; ++g){               // g=0: r-gate, g=1: z-gate
    #pragma unroll
    for (int nt=0;nt<4;nt++){
      int gt = g*4 + nt;
      f32x4 ai = {0.f,0.f,0.f,0.f};
      bf16x8 bi0 = *(const bf16x8*)(pkWih + (size_t)((gt*2+0)*64 + l)*8);
      bf16x8 bi1 = *(const bf16x8*)(pkWih + (size_t)((gt*2+1)*64 + l)*8);
      ai = __builtin_amdgcn_mfma_f32_16x16x32_bf16(xA0, bi0, ai, 0,0,0);
      ai = __builtin_amdgcn_mfma_f32_16x16x32_bf16(xA1, bi1, ai, 0,0,0);
      f32x4 ah = {0.f,0.f,0.f,0.f};
      if (HAS_H0){
        bf16x8 bh0 = *(const bf16x8*)(pkWhh + (size_t)((gt*2+0)*64 + l)*8);
        bf16x8 bh1 = *(const bf16x8*)(pkWhh + (size_t)((gt*2+1)*64 + l)*8);
        ah = __builtin_amdgcn_mfma_f32_16x16x32_bf16(hA0, bh0, ah, 0,0,0);
        ah = __builtin_amdgcn_mfma_f32_16x16x32_bf16(hA1, bh1, ah, 0,0,0);
      }
      #pragma unroll
      for (int r=0;r<4;r++){
        float bi_ = (g==0) ? bir[nt] : biz[nt];
        float bh_ = (g==0) ? bhr[nt] : bhz[nt];
        float v = sigf(ai[r] + bi_ + ah[r] + bh_);
        if (g==0) rv[nt*4+r] = v; else zv[nt*4+r] = v;
      }
    }
  }
  #pragma unroll
  for (int nt=0;nt<4;nt++){              // n-gate + GRU blend
    int gt = 8 + nt;
    f32x4 ai = {0.f,0.f,0.f,0.f};
    bf16x8 bi0 = *(const bf16x8*)(pkWih + (size_t)((gt*2+0)*64 + l)*8);
    bf16x8 bi1 = *(const bf16x8*)(pkWih + (size_t)((gt*2+1)*64 + l)*8);
    ai = __builtin_amdgcn_mfma_f32_16x16x32_bf16(xA0, bi0, ai, 0,0,0);
    ai = __builtin_amdgcn_mfma_f32_16x16x32_bf16(xA1, bi1, ai, 0,0,0);
    f32x4 ah = {0.f,0.f,0.f,0.f};
    if (HAS_H0){
      bf16x8 bh0 = *(const bf16x8*)(pkWhh + (size_t)((gt*2+0)*64 + l)*8);
      bf16x8 bh1 = *(const bf16x8*)(pkWhh + (size_t)((gt*2+1)*64 + l)*8);
      ah = __builtin_amdgcn_mfma_f32_16x16x32_bf16(hA0, bh0, ah, 0,0,0);
      ah = __builtin_amdgcn_mfma_f32_16x16x32_bf16(hA1, bh1, ah, 0,0,0);
    }
    #pragma unroll
    for (int r=0;r<4;r++){
      float gin = ai[r] + bin[nt];
      float ghn = ah[r] + bhn[nt];
      float rr  = rv[nt*4+r];
      float nn  = tanhf(fmaf(rr, ghn, gin));
      float z   = zv[nt*4+r];
      float h0v = 0.f;
      if (HAS_H0)
        h0v = bf2f(h16[(size_t)(n0 + w*16 + lg*4 + r)*HID + nt*16 + lr]);
      hv[nt*4+r] = (1.f - z)*nn + z*h0v;
    }
  }

  if (mode == 0){
    __syncthreads();
    #pragma unroll
    for (int nt=0;nt<4;nt++)
      #pragma unroll
      for (int r=0;r<4;r++){
        int m = lg*4 + r, col = nt*16 + lr;
        xlds[w*1024 + m*64 + (col ^ ((m&7)<<3))] = f2bf(hv[nt*4+r]);
      }
    __syncthreads();
    int rr2 = l >> 2, cc = l & 3;
    int n = n0 + w*16 + rr2;
    if (n < N_NODE){
      int base = w*1024 + rr2*64, s2 = (rr2&7)<<3;
      bf16x8 v0 = *(const bf16x8*)&xlds[base + ((cc*16)     ^ s2)];
      bf16x8 v1 = *(const bf16x8*)&xlds[base + ((cc*16 + 8) ^ s2)];
      *(bf16x8*)(h16_out + (size_t)n*HID + cc*16)     = v0;
      *(bf16x8*)(h16_out + (size_t)n*HID + cc*16 + 8) = v1;
    }
  } else {
    #pragma unroll
    for (int r=0;r<4;r++){
      float p = 0.f;
      #pragma unroll
      for (int nt=0;nt<4;nt++) p = fmaf(hv[nt*4+r], wfv[nt], p);
      p += __shfl_xor(p, 1);
      p += __shfl_xor(p, 2);
      p += __shfl_xor(p, 4);
      p += __shfl_xor(p, 8);
      if (lr == 0){
        int n = n0 + w*16 + lg*4 + r;
        if (n < N_NODE) score[n] = p;
      }
    }
  }
}

extern "C" void kernel_launch(void* const* d_in, const int* in_sizes, int n_in,
                              void* d_out, int out_size, void* d_ws, size_t ws_size,
                              hipStream_t stream)
{
  const int*   edges = (const int*)  d_in[0];
  const float* re    = (const float*)d_in[1];
  const float* Ws    = (const float*)d_in[2];
  const float* Wr    = (const float*)d_in[3];
  const float* ww    = (const float*)d_in[4];
  const float* wb    = (const float*)d_in[5];
  const float* Wh    = (const float*)d_in[6];
  const float* Wih   = (const float*)d_in[7];
  const float* Whh   = (const float*)d_in[8];
  const float* bih   = (const float*)d_in[9];
  const float* bhh   = (const float*)d_in[10];
  const float* wf    = (const float*)d_in[11];
  float* out = (float*)d_out;

  // workspace layout (u16 block, then f32, then 8B-aligned int2, then int)
  unsigned short* agg16  = (unsigned short*)d_ws;              // N_PAD*HID
  unsigned short* h16    = agg16 + (size_t)N_PAD*HID;          // N_PAD*HID
  unsigned short* srel16 = h16 + (size_t)N_PAD*HID;            // REL_VOCAB*HID
  unsigned short* re16   = srel16 + REL_VOCAB*HID;             // REL_VOCAB*HID
  unsigned short* pkWh   = re16 + REL_VOCAB*HID;               // 2*4096
  unsigned short* pkWih  = pkWh  + 2*4096;                     // 2*12288
  unsigned short* pkWhh  = pkWih + 2*12288;                    // 2*12288
  unsigned short* pkWs   = pkWhh + 2*12288;                    // 2048
  float* hrW1      = (float*)(pkWs + 2048);                    // REL_VOCAB*ATTN
  float* alphaS    = hrW1 + REL_VOCAB*ATTN;                    // N_EDGE
  int2*  pairS     = (int2*)(alphaS + N_EDGE);                 // N_EDGE int2
  int*   count     = (int*)(pairS + N_EDGE);                   // 100,004
  int*   startArr  = count + 100004;                           // 100,004
  int*   cursor    = startArr + 100004;                        // 100,004
  int*   bsum      = cursor + 100004;                          // 128
  int*   boff      = bsum + 128;                               // 128

  // ---- counting sort of edges by obj (packed rel/sub) ----
  k_zero<<<(100004/4+255)/256, 256, 0, stream>>>((float4*)count, 100004/4);
  k_hist<<<(N_EDGE+255)/256, 256, 0, stream>>>(edges, count);
  k_scan1<<<SCAN_NB, 1024, 0, stream>>>(count, startArr, bsum);
  k_scan2<<<1, 64, 0, stream>>>(bsum, boff);
  k_scan3<<<SCAN_NB, 1024, 0, stream>>>(startArr, boff, cursor);
  k_scatter<<<(N_EDGE+255)/256, 256, 0, stream>>>(edges, cursor, pairS);

  // ---- per-relation tables + packed bf16 weights ----
  k_pre<<<(REL_VOCAB*64+255)/256, 256, 0, stream>>>(re, Wr, ww, wb, srel16, re16, hrW1);
  k_wt<<<(116*64+255)/256, 256, 0, stream>>>(Wh, Wih, Whh, Ws, pkWh, pkWih, pkWhh, pkWs);

  const int NB_NODE2 = (N_NODE + 63) / 64;

  // ---- layer 0 ----
  k_agg0<<<(N_NODE*64)/256, 256, 0, stream>>>(startArr, pairS, srel16, agg16);
  k_node2<0><<<NB_NODE2, 256, 0, stream>>>(agg16, h16,
        pkWh, pkWih, pkWhh, bih, bhh, h16, wf, out, 0);

  // ---- layer 1 ----
  k_alphaM<<<N_EDGE/64, 256, 0, stream>>>(pairS, h16, hrW1, pkWs,
        ww + ATTN, wb + 1, alphaS);
  k_agg1<<<(N_NODE*64)/256, 256, 0, stream>>>(startArr, pairS, alphaS,
        h16, re16, agg16);
  k_node2<1><<<NB_NODE2, 256, 0, stream>>>(agg16, h16,
        pkWh + 4096, pkWih + 12288, pkWhh + 12288, bih + 3*HID, bhh + 3*HID,
        h16, wf, out, 1);
}